// Round 7
// baseline (206.376 us; speedup 1.0000x reference)
//
#include <hip/hip_runtime.h>
#include <hip/hip_bf16.h>

typedef __bf16 bf16_t;
typedef __bf16 bf16x2_t __attribute__((ext_vector_type(2)));
typedef __bf16 bf16x4_t __attribute__((ext_vector_type(4)));
typedef __bf16 bf16x8 __attribute__((ext_vector_type(8)));
typedef float f32x4 __attribute__((ext_vector_type(4)));
typedef float f32x16 __attribute__((ext_vector_type(16)));
typedef unsigned int u32x2 __attribute__((ext_vector_type(2)));

#define T_SEQ 1024
#define BATCH 8
#define NH 8
#define DH 128
#define HKDIM 1024  // NH*DH

static __device__ __forceinline__ f32x4 mfma16(bf16x8 a, bf16x8 b, f32x4 c) {
    return __builtin_amdgcn_mfma_f32_16x16x32_bf16(a, b, c, 0, 0, 0);
}
static __device__ __forceinline__ f32x16 mfma32(bf16x8 a, bf16x8 b, f32x16 c) {
    return __builtin_amdgcn_mfma_f32_32x32x16_bf16(a, b, c, 0, 0, 0);
}

static __device__ __forceinline__ unsigned pk2(float a, float b) {
    bf16x2_t t;
    t[0] = (bf16_t)a;
    t[1] = (bf16_t)b;
    union { bf16x2_t v; unsigned u; } c;
    c.v = t;
    return c.u;
}

static __device__ __forceinline__ bf16x8 cvt8(f32x4 a, f32x4 b) {
    bf16x8 o;
    o[0] = (bf16_t)a[0]; o[1] = (bf16_t)a[1];
    o[2] = (bf16_t)a[2]; o[3] = (bf16_t)a[3];
    o[4] = (bf16_t)b[0]; o[5] = (bf16_t)b[1];
    o[6] = (bf16_t)b[2]; o[7] = (bf16_t)b[3];
    return o;
}

// v_permlane32_swap via builtin: r[0] = {a.lo, b.lo}, r[1] = {a.hi, b.hi}
static __device__ __forceinline__ void plswap(unsigned& a, unsigned& b) {
    u32x2 r = __builtin_amdgcn_permlane32_swap(a, b, false, false);
    a = r[0];
    b = r[1];
}

// value of x from lane^32 (pure VALU, no DS)
static __device__ __forceinline__ float swap_partner(float x) {
    u32x2 r = __builtin_amdgcn_permlane32_swap(__float_as_uint(x),
                                               __float_as_uint(x), false, false);
    return __uint_as_float((threadIdx.x & 32) ? r[0] : r[1]);
}

// ---------------------------------------------------------------------------
// Kernel 1 (fused): QKV projection reading f32 inputs directly (inline bf16
//   conversion, identical RNE rounding to the old convert pass). K/Q written
//   [bh][t][d]; V written TRANSPOSED [bh][d][t] via LDS-staged 64x64 tile.
//   Side job: blockIdx.y == 48 converts Wo -> wob (bf16) for outproj.
// ---------------------------------------------------------------------------
__global__ __launch_bounds__(256) void proj_kernel(
        const float* __restrict__ x,
        const float* __restrict__ Wk, const float* __restrict__ bk,
        const float* __restrict__ Wq, const float* __restrict__ bq,
        const float* __restrict__ Wv, const float* __restrict__ bv,
        const float* __restrict__ Wo,
        bf16_t* __restrict__ kbuf, bf16_t* __restrict__ qbuf,
        bf16_t* __restrict__ vtbuf, bf16_t* __restrict__ wob) {
    if (blockIdx.y == 48) {
        // Wo f32 -> bf16 (128*1024 = 131072 elems = 128 blocks * 256 thr * 4)
        const int idx = (blockIdx.x * 256 + threadIdx.x) * 4;
        f32x4 v = *(const f32x4*)(Wo + idx);
        bf16x4_t o;
        o[0] = (bf16_t)v[0]; o[1] = (bf16_t)v[1];
        o[2] = (bf16_t)v[2]; o[3] = (bf16_t)v[3];
        *(bf16x4_t*)(wob + idx) = o;
        return;
    }
    const int lane = threadIdx.x & 63;
    const int wave = threadIdx.x >> 6;
    const int lr = lane & 15, lq = lane >> 4;
    const int rm0 = blockIdx.x * 64 + wave * 16;
    const int cb0 = blockIdx.y * 64;
    const int p = cb0 >> 10;
    const int cw0 = cb0 & 1023;
    const bool isV = (p == 2);
    const float* W = (p == 0) ? Wk : (p == 1 ? Wq : Wv);
    const float* bias_p = (p == 0) ? bk : (p == 1 ? bq : bv);

    __shared__ bf16_t vL[64][72];   // [d_local][t_local], 16B-aligned rows

    // A fragments from x (f32 -> bf16); x layout (t, b, d)
    bf16x8 aF[4];
    {
        const int row = rm0 + lr;
        const int bb = row >> 10, tt = row & 1023;
        const float* xr = x + ((size_t)tt * BATCH + bb) * DH + lq * 8;
#pragma unroll
        for (int kc = 0; kc < 4; ++kc) {
            f32x4 u0 = *(const f32x4*)(xr + kc * 32);
            f32x4 u1 = *(const f32x4*)(xr + kc * 32 + 4);
            aF[kc] = cvt8(u0, u1);
        }
    }

#pragma unroll
    for (int nc = 0; nc < 4; ++nc) {
        const int within = cw0 + nc * 16 + lr;
        f32x4 acc = {0.f, 0.f, 0.f, 0.f};
        const float* wr = W + (size_t)within * DH + lq * 8;
#pragma unroll
        for (int kc = 0; kc < 4; ++kc) {
            f32x4 u0 = *(const f32x4*)(wr + kc * 32);
            f32x4 u1 = *(const f32x4*)(wr + kc * 32 + 4);
            acc = mfma16(aF[kc], cvt8(u0, u1), acc);
        }
        const int h = within >> 7, d = within & 127;
        const float bias = bias_p[within];
        if (isV) {
            // stage V tile in LDS, transposed: vL[d_local][t_local]
#pragma unroll
            for (int r = 0; r < 4; ++r)
                vL[nc * 16 + lr][wave * 16 + lq * 4 + r] = (bf16_t)(acc[r] + bias);
        } else {
            bf16_t* dst = (p == 0) ? kbuf : qbuf;
#pragma unroll
            for (int r = 0; r < 4; ++r) {
                const int row = rm0 + lq * 4 + r;
                const int bb = row >> 10, tt = row & 1023;
                dst[((size_t)(bb * NH + h) * T_SEQ + tt) * DH + d] =
                    (bf16_t)(acc[r] + bias);
            }
        }
    }

    if (isV) {
        __syncthreads();
        const int tid = threadIdx.x;
        const int dl = tid >> 2;           // 0..63
        const int ts = (tid & 3) * 16;     // 0,16,32,48
        const int by = blockIdx.y - 32;
        const int h = by >> 1;
        const int d = (by & 1) * 64 + dl;
        const int bb = blockIdx.x >> 4;
        const int t0 = (blockIdx.x & 15) * 64;
        bf16x8 o0 = *(const bf16x8*)&vL[dl][ts];
        bf16x8 o1 = *(const bf16x8*)&vL[dl][ts + 8];
        bf16_t* dst = vtbuf + ((size_t)(bb * NH + h) * DH + d) * T_SEQ + t0 + ts;
        *(bf16x8*)dst = o0;
        *(bf16x8*)(dst + 8) = o1;
    }
}

// ---------------------------------------------------------------------------
// Kernel 2: flash attention (r4/r6 structure + V-prefetch one chunk ahead).
//   Roles: Q' := K_proj (rows i), K' := Q_proj (cols j), V := V_proj.
//   S^T = mfma32(K'[j], Q'[i]); 2 waves = 2 j-segments of one 32-row i-tile,
//   merged via LDS at the end. Zero DS ops / barriers in the main loop.
//   Both K and V fragments are prefetched one chunk ahead into the SAME
//   registers (issued after their consumers), hiding L3/HBM latency.
//   Grid: 2048 x 128thr; bx>>6 = reversed itile (heavy first), bx&63 = bh.
// ---------------------------------------------------------------------------
__global__ __launch_bounds__(128, 2) void attn_kernel(
        const bf16_t* __restrict__ kbuf, const bf16_t* __restrict__ qbuf,
        const bf16_t* __restrict__ vtb, bf16_t* __restrict__ obuf) {
    const int bx = blockIdx.x;
    const int itile = 31 - (bx >> 6);
    const int bh = bx & 63;
    const int b = bh >> 3, h = bh & 7;
    const int jseg = threadIdx.x >> 6;
    const int lane = threadIdx.x & 63;
    const int li = lane & 31;
    const int hi = lane >> 5;
    const int i0 = itile * 32;

    const bf16_t* Qp = kbuf + (size_t)bh * T_SEQ * DH;  // rows i (key positions)
    const bf16_t* Kp = qbuf + (size_t)bh * T_SEQ * DH;  // cols j (query positions)
    const bf16_t* Vt = vtb + (size_t)bh * DH * T_SEQ;   // [d][t]

    __shared__ float oL[128][32];   // [d][i] partial from jseg=1 (conflict-free)
    __shared__ float mlL[2][32];

    // persistent Q B-fragments: B[k=d][n=i], lane: i=li, k = s*16 + hi*8 + e
    bf16x8 qf[8];
#pragma unroll
    for (int s = 0; s < 8; ++s)
        qf[s] = *(const bf16x8*)(Qp + (size_t)(i0 + li) * DH + s * 16 + hi * 8);

    f32x16 oacc[4];
#pragma unroll
    for (int c = 0; c < 4; ++c)
#pragma unroll
        for (int e = 0; e < 16; ++e) oacc[c][e] = 0.f;

    float m = 0.f, l = 0.f;
    const float C = 0.08838834764831845f * 1.4426950408889634f;  // scale*log2e

    int jc = jseg;
    const bf16_t* kptr = Kp + (size_t)(jc * 32 + li) * DH + hi * 8;
    const bf16_t* vptr = Vt + (size_t)li * T_SEQ + jc * 32 + hi * 8;

    bf16x8 ka[8], va[8];
    if (jc <= itile) {
#pragma unroll
        for (int s = 0; s < 8; ++s) ka[s] = *(const bf16x8*)(kptr + s * 16);
#pragma unroll
        for (int n = 0; n < 4; ++n) {
            va[2 * n]     = *(const bf16x8*)(vptr + (size_t)(32 * n) * T_SEQ);
            va[2 * n + 1] = *(const bf16x8*)(vptr + (size_t)(32 * n) * T_SEQ + 16);
        }
    }

    for (; jc <= itile; jc += 2) {
        const bool more = (jc + 2 <= itile);

        // S^T = K' Q'^T : C[m=j][n=i]
        f32x16 sc;
#pragma unroll
        for (int e = 0; e < 16; ++e) sc[e] = 0.f;
        __builtin_amdgcn_s_setprio(1);
#pragma unroll
        for (int s = 0; s < 8; ++s) sc = mfma32(ka[s], qf[s], sc);
        __builtin_amdgcn_s_setprio(0);

        // prefetch next K chunk (overlaps softmax + PV)
        kptr += (size_t)64 * DH;
        vptr += 64;
        if (more) {
#pragma unroll
            for (int s = 0; s < 8; ++s) ka[s] = *(const bf16x8*)(kptr + s * 16);
        }

        // scale (+ diagonal causal mask: j > i)
        f32x16 sv;
#pragma unroll
        for (int e = 0; e < 16; ++e) sv[e] = sc[e] * C;
        if (jc == itile) {
#pragma unroll
            for (int r = 0; r < 16; ++r) {
                const int jrow = (r & 3) + 8 * (r >> 2) + 4 * hi;
                if (jrow > li) sv[r] = -1e30f;
            }
        }

        // row max: in-lane tree + cross-half permlane (no DS)
        float pm = sv[0];
#pragma unroll
        for (int r = 1; r < 16; ++r) pm = fmaxf(pm, sv[r]);
        pm = fmaxf(pm, swap_partner(pm));

        // T13 defer-rescale (log2 domain, THR=8)
        if (!__all(pm <= m + 8.f)) {
            const float mn = fmaxf(m, pm);
            const float f = exp2f(m - mn);
            m = mn;
            l *= f;
#pragma unroll
            for (int c = 0; c < 4; ++c)
#pragma unroll
                for (int e = 0; e < 16; ++e) oacc[c][e] *= f;
        }

        // P = 2^(sv - m), pack to bf16 pairs along j
        float ls = 0.f;
        unsigned Wp[8];
#pragma unroll
        for (int q = 0; q < 4; ++q) {
            const float p0 = exp2f(sv[4 * q + 0] - m);
            const float p1 = exp2f(sv[4 * q + 1] - m);
            const float p2 = exp2f(sv[4 * q + 2] - m);
            const float p3 = exp2f(sv[4 * q + 3] - m);
            ls += (p0 + p1) + (p2 + p3);
            Wp[2 * q] = pk2(p0, p1);
            Wp[2 * q + 1] = pk2(p2, p3);
        }
        l += ls;

        // redistribute P into B-fragments: 4 permlane32_swap (pure VALU)
        plswap(Wp[0], Wp[2]);
        plswap(Wp[1], Wp[3]);
        plswap(Wp[4], Wp[6]);
        plswap(Wp[5], Wp[7]);
        union { unsigned u[4]; bf16x8 v; } pb0, pb1;
        pb0.u[0] = Wp[0]; pb0.u[1] = Wp[1]; pb0.u[2] = Wp[2]; pb0.u[3] = Wp[3];
        pb1.u[0] = Wp[4]; pb1.u[1] = Wp[5]; pb1.u[2] = Wp[6]; pb1.u[3] = Wp[7];

        // PV: O^T[d][i] += V^T[d][j] P[j][i]
        __builtin_amdgcn_s_setprio(1);
        oacc[0] = mfma32(va[0], pb0.v, oacc[0]);
        oacc[0] = mfma32(va[1], pb1.v, oacc[0]);
        oacc[1] = mfma32(va[2], pb0.v, oacc[1]);
        oacc[1] = mfma32(va[3], pb1.v, oacc[1]);
        oacc[2] = mfma32(va[4], pb0.v, oacc[2]);
        oacc[2] = mfma32(va[5], pb1.v, oacc[2]);
        oacc[3] = mfma32(va[6], pb0.v, oacc[3]);
        oacc[3] = mfma32(va[7], pb1.v, oacc[3]);
        __builtin_amdgcn_s_setprio(0);

        // prefetch next V chunk (hides under next iteration's QK + softmax)
        if (more) {
#pragma unroll
            for (int n = 0; n < 4; ++n) {
                va[2 * n]     = *(const bf16x8*)(vptr + (size_t)(32 * n) * T_SEQ);
                va[2 * n + 1] = *(const bf16x8*)(vptr + (size_t)(32 * n) * T_SEQ + 16);
            }
        }
    }

    const float lfull = l + swap_partner(l);

    // merge the two j-segments via LDS
    if (jseg == 1) {
        if (lane < 32) { mlL[0][li] = m; mlL[1][li] = lfull; }
#pragma unroll
        for (int c = 0; c < 4; ++c)
#pragma unroll
            for (int r = 0; r < 16; ++r) {
                const int d = c * 32 + (r & 3) + 8 * (r >> 2) + 4 * hi;
                oL[d][li] = oacc[c][r];
            }
    }
    __syncthreads();
    if (jseg == 0) {
        const float m1 = mlL[0][li], l1 = mlL[1][li];
        const float mx = fmaxf(m, m1);
        const float fa = exp2f(m - mx), fb = exp2f(m1 - mx);
        const float inv = 1.f / (lfull * fa + l1 * fb);
        bf16_t* orow = obuf + ((size_t)b * T_SEQ + i0 + li) * HKDIM + h * DH;
#pragma unroll
        for (int c = 0; c < 4; ++c)
#pragma unroll
            for (int q = 0; q < 4; ++q) {
                bf16x4_t o4;
#pragma unroll
                for (int rr = 0; rr < 4; ++rr) {
                    const int d = c * 32 + q * 8 + 4 * hi + rr;
                    o4[rr] = (bf16_t)((oacc[c][4 * q + rr] * fa + oL[d][li] * fb) * inv);
                }
                *(bf16x4_t*)(orow + c * 32 + q * 8 + 4 * hi) = o4;
            }
    }
}

// ---------------------------------------------------------------------------
// Kernel 3: output projection, split-K over waves.
//   out[t][b][n] = sum_c ob[b][t][c]*Wo[n][c]+bo[n].  16 rows/block;
//   wave w covers kc in [8w, 8w+8); 8 col-groups x 8 indep MFMA chains;
//   32KB LDS reduction, wave w stores col-groups 2w, 2w+1.
// ---------------------------------------------------------------------------
__global__ __launch_bounds__(256) void outproj_kernel(
        const bf16_t* __restrict__ obuf, const bf16_t* __restrict__ wo,
        const float* __restrict__ bo, float* __restrict__ out) {
    const int lane = threadIdx.x & 63, wave = threadIdx.x >> 6;
    const int lr = lane & 15, lq = lane >> 4;
    const int rm0 = blockIdx.x * 16;
    __shared__ float red[4][8][256];   // [wave][g][lane*4]

    f32x4 acc[8];
#pragma unroll
    for (int g = 0; g < 8; ++g) acc[g] = {0.f, 0.f, 0.f, 0.f};
#pragma unroll 2
    for (int k8 = 0; k8 < 8; ++k8) {
        const int kc = wave * 8 + k8;
        bf16x8 aF = *(const bf16x8*)(obuf + (size_t)(rm0 + lr) * HKDIM + kc * 32 + lq * 8);
#pragma unroll
        for (int g = 0; g < 8; ++g) {
            bf16x8 bF = *(const bf16x8*)(wo + (size_t)(g * 16 + lr) * HKDIM + kc * 32 + lq * 8);
            acc[g] = mfma16(aF, bF, acc[g]);
        }
    }
#pragma unroll
    for (int g = 0; g < 8; ++g)
        *(f32x4*)&red[wave][g][lane * 4] = acc[g];
    __syncthreads();
#pragma unroll
    for (int gi = 0; gi < 2; ++gi) {
        const int g = wave * 2 + gi;
        f32x4 s = *(const f32x4*)&red[0][g][lane * 4];
#pragma unroll
        for (int w = 1; w < 4; ++w) {
            f32x4 t = *(const f32x4*)&red[w][g][lane * 4];
            s[0] += t[0]; s[1] += t[1]; s[2] += t[2]; s[3] += t[3];
        }
        const int col = g * 16 + lr;
        const float bias = bo[col];
#pragma unroll
        for (int r = 0; r < 4; ++r) {
            const int row = rm0 + lq * 4 + r;
            const int bb = row >> 10, tt = row & 1023;
            out[((size_t)tt * BATCH + bb) * DH + col] = s[r] + bias;
        }
    }
}

// ---------------------------------------------------------------------------
extern "C" void kernel_launch(void* const* d_in, const int* in_sizes, int n_in,
                              void* d_out, int out_size, void* d_ws, size_t ws_size,
                              hipStream_t stream) {
    const float* x  = (const float*)d_in[0];
    const float* Wk = (const float*)d_in[1];
    const float* bk = (const float*)d_in[2];
    const float* Wq = (const float*)d_in[3];
    const float* bq = (const float*)d_in[4];
    const float* Wv = (const float*)d_in[5];
    const float* bv = (const float*)d_in[6];
    const float* Wo = (const float*)d_in[7];
    const float* bo = (const float*)d_in[8];
    float* out = (float*)d_out;

    char* ws = (char*)d_ws;
    size_t off = 0;
    bf16_t* kb  = (bf16_t*)(ws + off); off += (size_t)BATCH * NH * T_SEQ * DH * 2;  // 16 MiB
    bf16_t* qb  = (bf16_t*)(ws + off); off += (size_t)BATCH * NH * T_SEQ * DH * 2;  // 16 MiB
    bf16_t* vtb = (bf16_t*)(ws + off); off += (size_t)BATCH * NH * T_SEQ * DH * 2;  // 16 MiB
    bf16_t* ob  = (bf16_t*)(ws + off); off += (size_t)BATCH * T_SEQ * HKDIM * 2;    // 16 MiB
    bf16_t* wob = (bf16_t*)(ws + off); off += (size_t)DH * HKDIM * 2;               // 0.25 MiB

    proj_kernel<<<dim3(128, 49), 256, 0, stream>>>(x, Wk, bk, Wq, bq, Wv, bv, Wo,
                                                   kb, qb, vtb, wob);
    attn_kernel<<<2048, 128, 0, stream>>>(kb, qb, vtb, ob);
    outproj_kernel<<<512, 256, 0, stream>>>(ob, wob, bo, out);
}

// Round 8
// 138.277 us; speedup vs baseline: 1.4925x; 1.4925x over previous
//
#include <hip/hip_runtime.h>
#include <hip/hip_bf16.h>

typedef __bf16 bf16_t;
typedef __bf16 bf16x2_t __attribute__((ext_vector_type(2)));
typedef __bf16 bf16x4_t __attribute__((ext_vector_type(4)));
typedef __bf16 bf16x8 __attribute__((ext_vector_type(8)));
typedef float f32x4 __attribute__((ext_vector_type(4)));
typedef float f32x16 __attribute__((ext_vector_type(16)));
typedef unsigned int u32x2 __attribute__((ext_vector_type(2)));

#define T_SEQ 1024
#define BATCH 8
#define NH 8
#define DH 128
#define HKDIM 1024  // NH*DH

static __device__ __forceinline__ f32x4 mfma16(bf16x8 a, bf16x8 b, f32x4 c) {
    return __builtin_amdgcn_mfma_f32_16x16x32_bf16(a, b, c, 0, 0, 0);
}
static __device__ __forceinline__ f32x16 mfma32(bf16x8 a, bf16x8 b, f32x16 c) {
    return __builtin_amdgcn_mfma_f32_32x32x16_bf16(a, b, c, 0, 0, 0);
}

static __device__ __forceinline__ unsigned pk2(float a, float b) {
    bf16x2_t t;
    t[0] = (bf16_t)a;
    t[1] = (bf16_t)b;
    union { bf16x2_t v; unsigned u; } c;
    c.v = t;
    return c.u;
}

// v_permlane32_swap via builtin: r[0] = {a.lo, b.lo}, r[1] = {a.hi, b.hi}
static __device__ __forceinline__ void plswap(unsigned& a, unsigned& b) {
    u32x2 r = __builtin_amdgcn_permlane32_swap(a, b, false, false);
    a = r[0];
    b = r[1];
}

// value of x from lane^32 (pure VALU, no DS)
static __device__ __forceinline__ float swap_partner(float x) {
    u32x2 r = __builtin_amdgcn_permlane32_swap(__float_as_uint(x),
                                               __float_as_uint(x), false, false);
    return __uint_as_float((threadIdx.x & 32) ? r[0] : r[1]);
}

// ---------------------------------------------------------------------------
// Kernel 1: convert inputs to bf16 working layouts (float4-vectorized).
// ---------------------------------------------------------------------------
__global__ __launch_bounds__(256) void convert_kernel(
        const float* __restrict__ x,
        const float* __restrict__ Wk, const float* __restrict__ Wq,
        const float* __restrict__ Wv, const float* __restrict__ Wo,
        bf16_t* __restrict__ xb, bf16_t* __restrict__ w3,
        bf16_t* __restrict__ wo) {
    const int n1 = T_SEQ * BATCH * DH;        // 1048576
    const int n2 = n1 + 3 * HKDIM * DH;       // +393216
    const int n3 = n2 + DH * HKDIM;           // +131072
    const int i = (blockIdx.x * 256 + threadIdx.x) * 4;
    if (i >= n3) return;
    const float* src;
    bf16_t* dst;
    if (i < n1) {
        int d = i & 127, t = (i >> 7) & 1023, b = i >> 17;
        src = x + (t * BATCH + b) * DH + d;
        dst = xb + i;
    } else if (i < n2) {
        int j = i - n1;
        int p = j >> 17;
        const float* W = (p == 0) ? Wk : (p == 1 ? Wq : Wv);
        src = W + (j & 131071);
        dst = w3 + j;
    } else {
        int j = i - n2;
        src = Wo + j;
        dst = wo + j;
    }
    f32x4 v = *(const f32x4*)src;
    bf16x4_t o;
    o[0] = (bf16_t)v[0]; o[1] = (bf16_t)v[1];
    o[2] = (bf16_t)v[2]; o[3] = (bf16_t)v[3];
    *(bf16x4_t*)dst = o;
}

// ---------------------------------------------------------------------------
// Kernel 2: QKV projection (bf16 reads; all 16 B-loads batched before MFMAs
//   so one L2 latency is amortized over 16 outstanding loads). K/Q written
//   [bh][t][d]; V written TRANSPOSED [bh][d][t] via LDS-staged 64x64 tile.
// ---------------------------------------------------------------------------
__global__ __launch_bounds__(256) void proj_kernel(
        const bf16_t* __restrict__ xb, const bf16_t* __restrict__ w3,
        const float* __restrict__ bk, const float* __restrict__ bq,
        const float* __restrict__ bv,
        bf16_t* __restrict__ kbuf, bf16_t* __restrict__ qbuf,
        bf16_t* __restrict__ vtbuf) {
    const int lane = threadIdx.x & 63;
    const int wave = threadIdx.x >> 6;
    const int lr = lane & 15, lq = lane >> 4;
    const int rm0 = blockIdx.x * 64 + wave * 16;
    const int cb0 = blockIdx.y * 64;
    const bool isV = (blockIdx.y >= 32);

    __shared__ bf16_t vL[64][72];   // [d_local][t_local], 16B-aligned rows

    bf16x8 aF[4];
#pragma unroll
    for (int kc = 0; kc < 4; ++kc)
        aF[kc] = *(const bf16x8*)(xb + (rm0 + lr) * DH + kc * 32 + lq * 8);

    // batch ALL B-fragment loads (16 outstanding) before the MFMA block
    bf16x8 kf[16];
#pragma unroll
    for (int nc = 0; nc < 4; ++nc)
#pragma unroll
        for (int kc = 0; kc < 4; ++kc)
            kf[nc * 4 + kc] =
                *(const bf16x8*)(w3 + (size_t)(cb0 + nc * 16 + lr) * DH + kc * 32 + lq * 8);

    f32x4 acc[4];
#pragma unroll
    for (int nc = 0; nc < 4; ++nc) acc[nc] = {0.f, 0.f, 0.f, 0.f};
#pragma unroll
    for (int nc = 0; nc < 4; ++nc)
#pragma unroll
        for (int kc = 0; kc < 4; ++kc)
            acc[nc] = mfma16(aF[kc], kf[nc * 4 + kc], acc[nc]);

#pragma unroll
    for (int nc = 0; nc < 4; ++nc) {
        const int col = cb0 + nc * 16 + lr;
        const int p = col >> 10, within = col & 1023;
        const int h = within >> 7, d = within & 127;
        const float bias = (p == 0) ? bk[within] : (p == 1 ? bq[within] : bv[within]);
        if (isV) {
#pragma unroll
            for (int r = 0; r < 4; ++r)
                vL[nc * 16 + lr][wave * 16 + lq * 4 + r] = (bf16_t)(acc[nc][r] + bias);
        } else {
            bf16_t* dst = (p == 0) ? kbuf : qbuf;
#pragma unroll
            for (int r = 0; r < 4; ++r) {
                const int row = rm0 + lq * 4 + r;
                const int bb = row >> 10, tt = row & 1023;
                dst[((size_t)(bb * NH + h) * T_SEQ + tt) * DH + d] =
                    (bf16_t)(acc[nc][r] + bias);
            }
        }
    }

    if (isV) {
        __syncthreads();
        const int tid = threadIdx.x;
        const int dl = tid >> 2;           // 0..63
        const int ts = (tid & 3) * 16;     // 0,16,32,48
        const int by = blockIdx.y - 32;
        const int h = by >> 1;
        const int d = (by & 1) * 64 + dl;
        const int bb = blockIdx.x >> 4;
        const int t0 = (blockIdx.x & 15) * 64;
        bf16x8 o0 = *(const bf16x8*)&vL[dl][ts];
        bf16x8 o1 = *(const bf16x8*)&vL[dl][ts + 8];
        bf16_t* dst = vtbuf + ((size_t)(bb * NH + h) * DH + d) * T_SEQ + t0 + ts;
        *(bf16x8*)dst = o0;
        *(bf16x8*)(dst + 8) = o1;
    }
}

// ---------------------------------------------------------------------------
// Kernel 3: flash attention, 128-row i-tile per block, LDS-shared K/V chunks.
//   Roles: Q' := K_proj (rows i), K' := Q_proj (cols j), V := V_proj.
//   4 waves = 4 i-subtiles of 32 rows each; every wave owns COMPLETE rows
//   (no merge). Per chunk: block stages K chunk [32][128] and V^T chunk
//   [128][32] into LDS (odd-granule padded rows), 2 uniform barriers, all
//   waves ds_read fragments. In-lane softmax + permlane P-shuffle unchanged.
//   Grid: 512; bx>>6 = reversed 128-tile (heavy first), bx&63 = bh.
// ---------------------------------------------------------------------------
__global__ __launch_bounds__(256, 2) void attn_kernel(
        const bf16_t* __restrict__ kbuf, const bf16_t* __restrict__ qbuf,
        const bf16_t* __restrict__ vtb, bf16_t* __restrict__ obuf) {
    const int bx = blockIdx.x;
    const int T = 7 - (bx >> 6);         // 128-row tile index, heavy first
    const int bh = bx & 63;
    const int b = bh >> 3, h = bh & 7;
    const int wv = threadIdx.x >> 6;     // i-subtile 0..3
    const int lane = threadIdx.x & 63;
    const int li = lane & 31;
    const int hi = lane >> 5;
    const int i0 = T * 128 + wv * 32;    // wave's first row
    const int cmax = 4 * T + wv;         // last chunk this wave computes
    const int nc = 4 * T + 4;            // chunks staged by the block

    const bf16_t* Qp = kbuf + (size_t)bh * T_SEQ * DH;  // rows i (key positions)
    const bf16_t* Kp = qbuf + (size_t)bh * T_SEQ * DH;  // cols j (query positions)
    const bf16_t* Vt = vtb + (size_t)bh * DH * T_SEQ;   // [d][t]

    __shared__ bf16_t kL[32][136];   // K chunk, 272B rows (17 granules, odd)
    __shared__ bf16_t vL[128][40];   // V^T chunk, 80B rows (5 granules, odd)

    // persistent Q B-fragments: lane: i=li, k = s*16 + hi*8 + e
    bf16x8 qf[8];
#pragma unroll
    for (int s = 0; s < 8; ++s)
        qf[s] = *(const bf16x8*)(Qp + (size_t)(i0 + li) * DH + s * 16 + hi * 8);

    f32x16 oacc[4];
#pragma unroll
    for (int c = 0; c < 4; ++c)
#pragma unroll
        for (int e = 0; e < 16; ++e) oacc[c][e] = 0.f;

    float m = 0.f, l = 0.f;
    const float C = 0.08838834764831845f * 1.4426950408889634f;  // scale*log2e

    // staging decomposition (thread-level)
    const int tid = threadIdx.x;
    const int kj = tid >> 3;             // K row 0..31
    const int kg = tid & 7;              // K granule-pair index
    const int vd = tid >> 1;             // V row 0..127
    const int vh = tid & 1;              // V half
    const bf16_t* kgsrc = Kp + (size_t)kj * DH + kg * 16;
    const bf16_t* vgsrc = Vt + (size_t)vd * T_SEQ + vh * 16;

    for (int c = 0; c < nc; ++c) {
        const int j0 = c * 32;
        __syncthreads();   // previous chunk's readers done
        {
            bf16x8 k0 = *(const bf16x8*)(kgsrc + (size_t)j0 * DH);
            bf16x8 k1 = *(const bf16x8*)(kgsrc + (size_t)j0 * DH + 8);
            bf16x8 v0 = *(const bf16x8*)(vgsrc + j0);
            bf16x8 v1 = *(const bf16x8*)(vgsrc + j0 + 8);
            *(bf16x8*)&kL[kj][kg * 16] = k0;
            *(bf16x8*)&kL[kj][kg * 16 + 8] = k1;
            *(bf16x8*)&vL[vd][vh * 16] = v0;
            *(bf16x8*)&vL[vd][vh * 16 + 8] = v1;
        }
        __syncthreads();
        if (c > cmax) continue;   // barriers stay uniform across the block

        // K fragments from LDS
        bf16x8 ka[8];
#pragma unroll
        for (int s = 0; s < 8; ++s)
            ka[s] = *(const bf16x8*)&kL[li][s * 16 + hi * 8];

        // S^T = K' Q'^T : C[m=j][n=i]
        f32x16 sc;
#pragma unroll
        for (int e = 0; e < 16; ++e) sc[e] = 0.f;
        __builtin_amdgcn_s_setprio(1);
#pragma unroll
        for (int s = 0; s < 8; ++s) sc = mfma32(ka[s], qf[s], sc);
        __builtin_amdgcn_s_setprio(0);

        // scale (+ diagonal causal mask: j > i)
        f32x16 sv;
#pragma unroll
        for (int e = 0; e < 16; ++e) sv[e] = sc[e] * C;
        if (c == cmax) {
#pragma unroll
            for (int r = 0; r < 16; ++r) {
                const int jrow = (r & 3) + 8 * (r >> 2) + 4 * hi;
                if (jrow > li) sv[r] = -1e30f;
            }
        }

        // row max: in-lane tree + cross-half permlane (no DS)
        float pm = sv[0];
#pragma unroll
        for (int r = 1; r < 16; ++r) pm = fmaxf(pm, sv[r]);
        pm = fmaxf(pm, swap_partner(pm));

        // T13 defer-rescale (log2 domain, THR=8)
        if (!__all(pm <= m + 8.f)) {
            const float mn = fmaxf(m, pm);
            const float f = exp2f(m - mn);
            m = mn;
            l *= f;
#pragma unroll
            for (int cc = 0; cc < 4; ++cc)
#pragma unroll
                for (int e = 0; e < 16; ++e) oacc[cc][e] *= f;
        }

        // P = 2^(sv - m), pack to bf16 pairs along j
        float ls = 0.f;
        unsigned Wp[8];
#pragma unroll
        for (int q = 0; q < 4; ++q) {
            const float p0 = exp2f(sv[4 * q + 0] - m);
            const float p1 = exp2f(sv[4 * q + 1] - m);
            const float p2 = exp2f(sv[4 * q + 2] - m);
            const float p3 = exp2f(sv[4 * q + 3] - m);
            ls += (p0 + p1) + (p2 + p3);
            Wp[2 * q] = pk2(p0, p1);
            Wp[2 * q + 1] = pk2(p2, p3);
        }
        l += ls;

        // redistribute P into B-fragments: 4 permlane32_swap (pure VALU)
        plswap(Wp[0], Wp[2]);
        plswap(Wp[1], Wp[3]);
        plswap(Wp[4], Wp[6]);
        plswap(Wp[5], Wp[7]);
        union { unsigned u[4]; bf16x8 v; } pb0, pb1;
        pb0.u[0] = Wp[0]; pb0.u[1] = Wp[1]; pb0.u[2] = Wp[2]; pb0.u[3] = Wp[3];
        pb1.u[0] = Wp[4]; pb1.u[1] = Wp[5]; pb1.u[2] = Wp[6]; pb1.u[3] = Wp[7];

        // V fragments from LDS; PV: O^T[d][i] += V^T[d][j] P[j][i]
        bf16x8 va[8];
#pragma unroll
        for (int n = 0; n < 4; ++n) {
            va[2 * n]     = *(const bf16x8*)&vL[li + 32 * n][hi * 8];
            va[2 * n + 1] = *(const bf16x8*)&vL[li + 32 * n][hi * 8 + 16];
        }
        __builtin_amdgcn_s_setprio(1);
        oacc[0] = mfma32(va[0], pb0.v, oacc[0]);
        oacc[0] = mfma32(va[1], pb1.v, oacc[0]);
        oacc[1] = mfma32(va[2], pb0.v, oacc[1]);
        oacc[1] = mfma32(va[3], pb1.v, oacc[1]);
        oacc[2] = mfma32(va[4], pb0.v, oacc[2]);
        oacc[2] = mfma32(va[5], pb1.v, oacc[2]);
        oacc[3] = mfma32(va[6], pb0.v, oacc[3]);
        oacc[3] = mfma32(va[7], pb1.v, oacc[3]);
        __builtin_amdgcn_s_setprio(0);
    }

    // epilogue: each wave owns complete rows — normalize and store directly
    const float lfull = l + swap_partner(l);
    const float inv = 1.f / lfull;
    bf16_t* orow = obuf + ((size_t)b * T_SEQ + i0 + li) * HKDIM + h * DH;
#pragma unroll
    for (int c = 0; c < 4; ++c)
#pragma unroll
        for (int q = 0; q < 4; ++q) {
            bf16x4_t o4;
#pragma unroll
            for (int rr = 0; rr < 4; ++rr)
                o4[rr] = (bf16_t)(oacc[c][4 * q + rr] * inv);
            *(bf16x4_t*)(orow + c * 32 + q * 8 + 4 * hi) = o4;
        }
}

// ---------------------------------------------------------------------------
// Kernel 4: output projection, split-K over waves.
// ---------------------------------------------------------------------------
__global__ __launch_bounds__(256) void outproj_kernel(
        const bf16_t* __restrict__ obuf, const bf16_t* __restrict__ wo,
        const float* __restrict__ bo, float* __restrict__ out) {
    const int lane = threadIdx.x & 63, wave = threadIdx.x >> 6;
    const int lr = lane & 15, lq = lane >> 4;
    const int rm0 = blockIdx.x * 16;
    __shared__ float red[4][8][256];   // [wave][g][lane*4]

    f32x4 acc[8];
#pragma unroll
    for (int g = 0; g < 8; ++g) acc[g] = {0.f, 0.f, 0.f, 0.f};
#pragma unroll 2
    for (int k8 = 0; k8 < 8; ++k8) {
        const int kc = wave * 8 + k8;
        bf16x8 aF = *(const bf16x8*)(obuf + (size_t)(rm0 + lr) * HKDIM + kc * 32 + lq * 8);
#pragma unroll
        for (int g = 0; g < 8; ++g) {
            bf16x8 bF = *(const bf16x8*)(wo + (size_t)(g * 16 + lr) * HKDIM + kc * 32 + lq * 8);
            acc[g] = mfma16(aF, bF, acc[g]);
        }
    }
#pragma unroll
    for (int g = 0; g < 8; ++g)
        *(f32x4*)&red[wave][g][lane * 4] = acc[g];
    __syncthreads();
#pragma unroll
    for (int gi = 0; gi < 2; ++gi) {
        const int g = wave * 2 + gi;
        f32x4 s = *(const f32x4*)&red[0][g][lane * 4];
#pragma unroll
        for (int w = 1; w < 4; ++w) {
            f32x4 t = *(const f32x4*)&red[w][g][lane * 4];
            s[0] += t[0]; s[1] += t[1]; s[2] += t[2]; s[3] += t[3];
        }
        const int col = g * 16 + lr;
        const float bias = bo[col];
#pragma unroll
        for (int r = 0; r < 4; ++r) {
            const int row = rm0 + lq * 4 + r;
            const int bb = row >> 10, tt = row & 1023;
            out[((size_t)tt * BATCH + bb) * DH + col] = s[r] + bias;
        }
    }
}

// ---------------------------------------------------------------------------
extern "C" void kernel_launch(void* const* d_in, const int* in_sizes, int n_in,
                              void* d_out, int out_size, void* d_ws, size_t ws_size,
                              hipStream_t stream) {
    const float* x  = (const float*)d_in[0];
    const float* Wk = (const float*)d_in[1];
    const float* bk = (const float*)d_in[2];
    const float* Wq = (const float*)d_in[3];
    const float* bq = (const float*)d_in[4];
    const float* Wv = (const float*)d_in[5];
    const float* bv = (const float*)d_in[6];
    const float* Wo = (const float*)d_in[7];
    const float* bo = (const float*)d_in[8];
    float* out = (float*)d_out;

    char* ws = (char*)d_ws;
    size_t off = 0;
    bf16_t* xb  = (bf16_t*)(ws + off); off += (size_t)BATCH * T_SEQ * DH * 2;       // 2 MiB
    bf16_t* w3  = (bf16_t*)(ws + off); off += (size_t)3 * HKDIM * DH * 2;           // 0.75 MiB
    bf16_t* wo  = (bf16_t*)(ws + off); off += (size_t)DH * HKDIM * 2;               // 0.25 MiB
    bf16_t* kb  = (bf16_t*)(ws + off); off += (size_t)BATCH * NH * T_SEQ * DH * 2;  // 16 MiB
    bf16_t* qb  = (bf16_t*)(ws + off); off += (size_t)BATCH * NH * T_SEQ * DH * 2;  // 16 MiB
    bf16_t* vtb = (bf16_t*)(ws + off); off += (size_t)BATCH * NH * T_SEQ * DH * 2;  // 16 MiB
    bf16_t* ob  = (bf16_t*)(ws + off); off += (size_t)BATCH * T_SEQ * HKDIM * 2;    // 16 MiB

    convert_kernel<<<1536, 256, 0, stream>>>(x, Wk, Wq, Wv, Wo, xb, w3, wo);
    proj_kernel<<<dim3(128, 48), 256, 0, stream>>>(xb, w3, bk, bq, bv, kb, qb, vtb);
    attn_kernel<<<512, 256, 0, stream>>>(kb, qb, vtb, ob);
    outproj_kernel<<<512, 256, 0, stream>>>(ob, wo, bo, out);
}

// Round 9
// 120.426 us; speedup vs baseline: 1.7137x; 1.1482x over previous
//
#include <hip/hip_runtime.h>
#include <hip/hip_bf16.h>

typedef __bf16 bf16_t;
typedef __bf16 bf16x2_t __attribute__((ext_vector_type(2)));
typedef __bf16 bf16x4_t __attribute__((ext_vector_type(4)));
typedef __bf16 bf16x8 __attribute__((ext_vector_type(8)));
typedef float f32x4 __attribute__((ext_vector_type(4)));
typedef float f32x16 __attribute__((ext_vector_type(16)));
typedef unsigned int u32x2 __attribute__((ext_vector_type(2)));

#define T_SEQ 1024
#define BATCH 8
#define NH 8
#define DH 128
#define HKDIM 1024  // NH*DH

static __device__ __forceinline__ f32x4 mfma16(bf16x8 a, bf16x8 b, f32x4 c) {
    return __builtin_amdgcn_mfma_f32_16x16x32_bf16(a, b, c, 0, 0, 0);
}
static __device__ __forceinline__ f32x16 mfma32(bf16x8 a, bf16x8 b, f32x16 c) {
    return __builtin_amdgcn_mfma_f32_32x32x16_bf16(a, b, c, 0, 0, 0);
}

static __device__ __forceinline__ unsigned pk2(float a, float b) {
    bf16x2_t t;
    t[0] = (bf16_t)a;
    t[1] = (bf16_t)b;
    union { bf16x2_t v; unsigned u; } c;
    c.v = t;
    return c.u;
}

// v_permlane32_swap via builtin: r[0] = {a.lo, b.lo}, r[1] = {a.hi, b.hi}
static __device__ __forceinline__ void plswap(unsigned& a, unsigned& b) {
    u32x2 r = __builtin_amdgcn_permlane32_swap(a, b, false, false);
    a = r[0];
    b = r[1];
}

// value of x from lane^32 (pure VALU, no DS)
static __device__ __forceinline__ float swap_partner(float x) {
    u32x2 r = __builtin_amdgcn_permlane32_swap(__float_as_uint(x),
                                               __float_as_uint(x), false, false);
    return __uint_as_float((threadIdx.x & 32) ? r[0] : r[1]);
}

// ---------------------------------------------------------------------------
// Kernel 1: convert inputs to bf16 working layouts (float4-vectorized).
// ---------------------------------------------------------------------------
__global__ __launch_bounds__(256) void convert_kernel(
        const float* __restrict__ x,
        const float* __restrict__ Wk, const float* __restrict__ Wq,
        const float* __restrict__ Wv, const float* __restrict__ Wo,
        bf16_t* __restrict__ xb, bf16_t* __restrict__ w3,
        bf16_t* __restrict__ wo) {
    const int n1 = T_SEQ * BATCH * DH;        // 1048576
    const int n2 = n1 + 3 * HKDIM * DH;       // +393216
    const int n3 = n2 + DH * HKDIM;           // +131072
    const int i = (blockIdx.x * 256 + threadIdx.x) * 4;
    if (i >= n3) return;
    const float* src;
    bf16_t* dst;
    if (i < n1) {
        int d = i & 127, t = (i >> 7) & 1023, b = i >> 17;
        src = x + (t * BATCH + b) * DH + d;
        dst = xb + i;
    } else if (i < n2) {
        int j = i - n1;
        int p = j >> 17;
        const float* W = (p == 0) ? Wk : (p == 1 ? Wq : Wv);
        src = W + (j & 131071);
        dst = w3 + j;
    } else {
        int j = i - n2;
        src = Wo + j;
        dst = wo + j;
    }
    f32x4 v = *(const f32x4*)src;
    bf16x4_t o;
    o[0] = (bf16_t)v[0]; o[1] = (bf16_t)v[1];
    o[2] = (bf16_t)v[2]; o[3] = (bf16_t)v[3];
    *(bf16x4_t*)dst = o;
}

// ---------------------------------------------------------------------------
// Kernel 2: QKV projection, 128-row blocks (2 row-groups/wave, B-frags
//   reused 2x). K/Q use SWAPPED operand order (W as A, x as B) so each lane
//   holds one t-row with 4 consecutive d -> one 8-B full-sector store per
//   (rg,nc): no L2 read-modify-write. V keeps x-as-A order + LDS transpose,
//   written [bh][d][t] as contiguous 16-B stores.
// ---------------------------------------------------------------------------
__global__ __launch_bounds__(256) void proj_kernel(
        const bf16_t* __restrict__ xb, const bf16_t* __restrict__ w3,
        const float* __restrict__ bk, const float* __restrict__ bq,
        const float* __restrict__ bv,
        bf16_t* __restrict__ kbuf, bf16_t* __restrict__ qbuf,
        bf16_t* __restrict__ vtbuf) {
    const int lane = threadIdx.x & 63;
    const int wave = threadIdx.x >> 6;
    const int lr = lane & 15, lq = lane >> 4;
    const int rm_base = blockIdx.x * 128;
    const int cb0 = blockIdx.y * 64;
    const int p = cb0 >> 10;
    const int cw0 = cb0 & 1023;          // col within projection (0..960)
    const int h = cw0 >> 7;
    const int dbase = cw0 & 127;         // 0 or 64
    const bool isV = (p == 2);

    __shared__ bf16_t vL[64][136];       // [d_local][t_local 0..127], padded

    bf16x8 aF[2][4];
#pragma unroll
    for (int rg = 0; rg < 2; ++rg) {
        const int row = rm_base + rg * 64 + wave * 16 + lr;
#pragma unroll
        for (int kc = 0; kc < 4; ++kc)
            aF[rg][kc] = *(const bf16x8*)(xb + (size_t)row * DH + kc * 32 + lq * 8);
    }
    bf16x8 kf[16];
#pragma unroll
    for (int nc = 0; nc < 4; ++nc)
#pragma unroll
        for (int kc = 0; kc < 4; ++kc)
            kf[nc * 4 + kc] =
                *(const bf16x8*)(w3 + (size_t)(cb0 + nc * 16 + lr) * DH + kc * 32 + lq * 8);

    f32x4 acc[2][4];
#pragma unroll
    for (int rg = 0; rg < 2; ++rg)
#pragma unroll
        for (int nc = 0; nc < 4; ++nc) acc[rg][nc] = {0.f, 0.f, 0.f, 0.f};

    if (!isV) {
        // C[m = w-col][n = x-row]: lane n=lr (t-row), m = lq*4+r (d, consecutive)
#pragma unroll
        for (int rg = 0; rg < 2; ++rg)
#pragma unroll
            for (int nc = 0; nc < 4; ++nc)
#pragma unroll
                for (int kc = 0; kc < 4; ++kc)
                    acc[rg][nc] = mfma16(kf[nc * 4 + kc], aF[rg][kc], acc[rg][nc]);

        const float* bias_p = (p == 0) ? bk : bq;
        bf16_t* dst = (p == 0) ? kbuf : qbuf;
#pragma unroll
        for (int nc = 0; nc < 4; ++nc) {
            const f32x4 b4 = *(const f32x4*)(bias_p + cw0 + nc * 16 + lq * 4);
#pragma unroll
            for (int rg = 0; rg < 2; ++rg) {
                const int row = rm_base + rg * 64 + wave * 16 + lr;
                const int bb = row >> 10, tt = row & 1023;
                bf16x4_t o4;
#pragma unroll
                for (int r = 0; r < 4; ++r)
                    o4[r] = (bf16_t)(acc[rg][nc][r] + b4[r]);
                *(bf16x4_t*)(dst + ((size_t)(bb * NH + h) * T_SEQ + tt) * DH +
                             dbase + nc * 16 + lq * 4) = o4;
            }
        }
    } else {
        // C[m = x-row][n = w-col]: lane n=lr (d), m = lq*4+r (t)
#pragma unroll
        for (int rg = 0; rg < 2; ++rg)
#pragma unroll
            for (int nc = 0; nc < 4; ++nc)
#pragma unroll
                for (int kc = 0; kc < 4; ++kc)
                    acc[rg][nc] = mfma16(aF[rg][kc], kf[nc * 4 + kc], acc[rg][nc]);

#pragma unroll
        for (int nc = 0; nc < 4; ++nc) {
            const float bias = bv[cw0 + nc * 16 + lr];
#pragma unroll
            for (int rg = 0; rg < 2; ++rg)
#pragma unroll
                for (int r = 0; r < 4; ++r)
                    vL[nc * 16 + lr][rg * 64 + wave * 16 + lq * 4 + r] =
                        (bf16_t)(acc[rg][nc][r] + bias);
        }
        __syncthreads();
        // write out: 64 d-rows x 128 t, 64 B per thread, coalesced
        const int tid = threadIdx.x;
        const int dl = tid >> 2;             // 0..63
        const int toff = (tid & 3) * 32;     // elements within the 128-t row
        const int bb = blockIdx.x >> 3;
        const int t0 = (blockIdx.x & 7) * 128;
        const int dg = dbase + dl;
        bf16_t* dst = vtbuf + ((size_t)(bb * NH + h) * DH + dg) * T_SEQ + t0 + toff;
#pragma unroll
        for (int i = 0; i < 4; ++i)
            *(bf16x8*)(dst + i * 8) = *(const bf16x8*)&vL[dl][toff + i * 8];
    }
}

// ---------------------------------------------------------------------------
// Kernel 3: flash attention, 128-row i-tile per block, LDS-shared K/V chunks
//   (unchanged from r8).
// ---------------------------------------------------------------------------
__global__ __launch_bounds__(256, 2) void attn_kernel(
        const bf16_t* __restrict__ kbuf, const bf16_t* __restrict__ qbuf,
        const bf16_t* __restrict__ vtb, bf16_t* __restrict__ obuf) {
    const int bx = blockIdx.x;
    const int T = 7 - (bx >> 6);         // 128-row tile index, heavy first
    const int bh = bx & 63;
    const int b = bh >> 3, h = bh & 7;
    const int wv = threadIdx.x >> 6;     // i-subtile 0..3
    const int lane = threadIdx.x & 63;
    const int li = lane & 31;
    const int hi = lane >> 5;
    const int i0 = T * 128 + wv * 32;    // wave's first row
    const int cmax = 4 * T + wv;         // last chunk this wave computes
    const int nc = 4 * T + 4;            // chunks staged by the block

    const bf16_t* Qp = kbuf + (size_t)bh * T_SEQ * DH;  // rows i (key positions)
    const bf16_t* Kp = qbuf + (size_t)bh * T_SEQ * DH;  // cols j (query positions)
    const bf16_t* Vt = vtb + (size_t)bh * DH * T_SEQ;   // [d][t]

    __shared__ bf16_t kL[32][136];   // K chunk, 272B rows (17 granules, odd)
    __shared__ bf16_t vL[128][40];   // V^T chunk, 80B rows (5 granules, odd)

    // persistent Q B-fragments: lane: i=li, k = s*16 + hi*8 + e
    bf16x8 qf[8];
#pragma unroll
    for (int s = 0; s < 8; ++s)
        qf[s] = *(const bf16x8*)(Qp + (size_t)(i0 + li) * DH + s * 16 + hi * 8);

    f32x16 oacc[4];
#pragma unroll
    for (int c = 0; c < 4; ++c)
#pragma unroll
        for (int e = 0; e < 16; ++e) oacc[c][e] = 0.f;

    float m = 0.f, l = 0.f;
    const float C = 0.08838834764831845f * 1.4426950408889634f;  // scale*log2e

    // staging decomposition (thread-level)
    const int tid = threadIdx.x;
    const int kj = tid >> 3;             // K row 0..31
    const int kg = tid & 7;              // K granule-pair index
    const int vd = tid >> 1;             // V row 0..127
    const int vh = tid & 1;              // V half
    const bf16_t* kgsrc = Kp + (size_t)kj * DH + kg * 16;
    const bf16_t* vgsrc = Vt + (size_t)vd * T_SEQ + vh * 16;

    for (int c = 0; c < nc; ++c) {
        const int j0 = c * 32;
        __syncthreads();   // previous chunk's readers done
        {
            bf16x8 k0 = *(const bf16x8*)(kgsrc + (size_t)j0 * DH);
            bf16x8 k1 = *(const bf16x8*)(kgsrc + (size_t)j0 * DH + 8);
            bf16x8 v0 = *(const bf16x8*)(vgsrc + j0);
            bf16x8 v1 = *(const bf16x8*)(vgsrc + j0 + 8);
            *(bf16x8*)&kL[kj][kg * 16] = k0;
            *(bf16x8*)&kL[kj][kg * 16 + 8] = k1;
            *(bf16x8*)&vL[vd][vh * 16] = v0;
            *(bf16x8*)&vL[vd][vh * 16 + 8] = v1;
        }
        __syncthreads();
        if (c > cmax) continue;   // barriers stay uniform across the block

        // K fragments from LDS
        bf16x8 ka[8];
#pragma unroll
        for (int s = 0; s < 8; ++s)
            ka[s] = *(const bf16x8*)&kL[li][s * 16 + hi * 8];

        // S^T = K' Q'^T : C[m=j][n=i]
        f32x16 sc;
#pragma unroll
        for (int e = 0; e < 16; ++e) sc[e] = 0.f;
        __builtin_amdgcn_s_setprio(1);
#pragma unroll
        for (int s = 0; s < 8; ++s) sc = mfma32(ka[s], qf[s], sc);
        __builtin_amdgcn_s_setprio(0);

        // scale (+ diagonal causal mask: j > i)
        f32x16 sv;
#pragma unroll
        for (int e = 0; e < 16; ++e) sv[e] = sc[e] * C;
        if (c == cmax) {
#pragma unroll
            for (int r = 0; r < 16; ++r) {
                const int jrow = (r & 3) + 8 * (r >> 2) + 4 * hi;
                if (jrow > li) sv[r] = -1e30f;
            }
        }

        // row max: in-lane tree + cross-half permlane (no DS)
        float pm = sv[0];
#pragma unroll
        for (int r = 1; r < 16; ++r) pm = fmaxf(pm, sv[r]);
        pm = fmaxf(pm, swap_partner(pm));

        // T13 defer-rescale (log2 domain, THR=8)
        if (!__all(pm <= m + 8.f)) {
            const float mn = fmaxf(m, pm);
            const float f = exp2f(m - mn);
            m = mn;
            l *= f;
#pragma unroll
            for (int cc = 0; cc < 4; ++cc)
#pragma unroll
                for (int e = 0; e < 16; ++e) oacc[cc][e] *= f;
        }

        // P = 2^(sv - m), pack to bf16 pairs along j
        float ls = 0.f;
        unsigned Wp[8];
#pragma unroll
        for (int q = 0; q < 4; ++q) {
            const float p0 = exp2f(sv[4 * q + 0] - m);
            const float p1 = exp2f(sv[4 * q + 1] - m);
            const float p2 = exp2f(sv[4 * q + 2] - m);
            const float p3 = exp2f(sv[4 * q + 3] - m);
            ls += (p0 + p1) + (p2 + p3);
            Wp[2 * q] = pk2(p0, p1);
            Wp[2 * q + 1] = pk2(p2, p3);
        }
        l += ls;

        // redistribute P into B-fragments: 4 permlane32_swap (pure VALU)
        plswap(Wp[0], Wp[2]);
        plswap(Wp[1], Wp[3]);
        plswap(Wp[4], Wp[6]);
        plswap(Wp[5], Wp[7]);
        union { unsigned u[4]; bf16x8 v; } pb0, pb1;
        pb0.u[0] = Wp[0]; pb0.u[1] = Wp[1]; pb0.u[2] = Wp[2]; pb0.u[3] = Wp[3];
        pb1.u[0] = Wp[4]; pb1.u[1] = Wp[5]; pb1.u[2] = Wp[6]; pb1.u[3] = Wp[7];

        // V fragments from LDS; PV: O^T[d][i] += V^T[d][j] P[j][i]
        bf16x8 va[8];
#pragma unroll
        for (int n = 0; n < 4; ++n) {
            va[2 * n]     = *(const bf16x8*)&vL[li + 32 * n][hi * 8];
            va[2 * n + 1] = *(const bf16x8*)&vL[li + 32 * n][hi * 8 + 16];
        }
        __builtin_amdgcn_s_setprio(1);
        oacc[0] = mfma32(va[0], pb0.v, oacc[0]);
        oacc[0] = mfma32(va[1], pb1.v, oacc[0]);
        oacc[1] = mfma32(va[2], pb0.v, oacc[1]);
        oacc[1] = mfma32(va[3], pb1.v, oacc[1]);
        oacc[2] = mfma32(va[4], pb0.v, oacc[2]);
        oacc[2] = mfma32(va[5], pb1.v, oacc[2]);
        oacc[3] = mfma32(va[6], pb0.v, oacc[3]);
        oacc[3] = mfma32(va[7], pb1.v, oacc[3]);
        __builtin_amdgcn_s_setprio(0);
    }

    // epilogue: each wave owns complete rows — normalize and store directly
    const float lfull = l + swap_partner(l);
    const float inv = 1.f / lfull;
    bf16_t* orow = obuf + ((size_t)b * T_SEQ + i0 + li) * HKDIM + h * DH;
#pragma unroll
    for (int c = 0; c < 4; ++c)
#pragma unroll
        for (int q = 0; q < 4; ++q) {
            bf16x4_t o4;
#pragma unroll
            for (int rr = 0; rr < 4; ++rr)
                o4[rr] = (bf16_t)(oacc[c][4 * q + rr] * inv);
            *(bf16x4_t*)(orow + c * 32 + q * 8 + 4 * hi) = o4;
        }
}

// ---------------------------------------------------------------------------
// Kernel 4: output projection, split-K over waves (unchanged from r8).
// ---------------------------------------------------------------------------
__global__ __launch_bounds__(256) void outproj_kernel(
        const bf16_t* __restrict__ obuf, const bf16_t* __restrict__ wo,
        const float* __restrict__ bo, float* __restrict__ out) {
    const int lane = threadIdx.x & 63, wave = threadIdx.x >> 6;
    const int lr = lane & 15, lq = lane >> 4;
    const int rm0 = blockIdx.x * 16;
    __shared__ float red[4][8][256];   // [wave][g][lane*4]

    f32x4 acc[8];
#pragma unroll
    for (int g = 0; g < 8; ++g) acc[g] = {0.f, 0.f, 0.f, 0.f};
#pragma unroll 2
    for (int k8 = 0; k8 < 8; ++k8) {
        const int kc = wave * 8 + k8;
        bf16x8 aF = *(const bf16x8*)(obuf + (size_t)(rm0 + lr) * HKDIM + kc * 32 + lq * 8);
#pragma unroll
        for (int g = 0; g < 8; ++g) {
            bf16x8 bF = *(const bf16x8*)(wo + (size_t)(g * 16 + lr) * HKDIM + kc * 32 + lq * 8);
            acc[g] = mfma16(aF, bF, acc[g]);
        }
    }
#pragma unroll
    for (int g = 0; g < 8; ++g)
        *(f32x4*)&red[wave][g][lane * 4] = acc[g];
    __syncthreads();
#pragma unroll
    for (int gi = 0; gi < 2; ++gi) {
        const int g = wave * 2 + gi;
        f32x4 s = *(const f32x4*)&red[0][g][lane * 4];
#pragma unroll
        for (int w = 1; w < 4; ++w) {
            f32x4 t = *(const f32x4*)&red[w][g][lane * 4];
            s[0] += t[0]; s[1] += t[1]; s[2] += t[2]; s[3] += t[3];
        }
        const int col = g * 16 + lr;
        const float bias = bo[col];
#pragma unroll
        for (int r = 0; r < 4; ++r) {
            const int row = rm0 + lq * 4 + r;
            const int bb = row >> 10, tt = row & 1023;
            out[((size_t)tt * BATCH + bb) * DH + col] = s[r] + bias;
        }
    }
}

// ---------------------------------------------------------------------------
extern "C" void kernel_launch(void* const* d_in, const int* in_sizes, int n_in,
                              void* d_out, int out_size, void* d_ws, size_t ws_size,
                              hipStream_t stream) {
    const float* x  = (const float*)d_in[0];
    const float* Wk = (const float*)d_in[1];
    const float* bk = (const float*)d_in[2];
    const float* Wq = (const float*)d_in[3];
    const float* bq = (const float*)d_in[4];
    const float* Wv = (const float*)d_in[5];
    const float* bv = (const float*)d_in[6];
    const float* Wo = (const float*)d_in[7];
    const float* bo = (const float*)d_in[8];
    float* out = (float*)d_out;

    char* ws = (char*)d_ws;
    size_t off = 0;
    bf16_t* xb  = (bf16_t*)(ws + off); off += (size_t)BATCH * T_SEQ * DH * 2;       // 2 MiB
    bf16_t* w3  = (bf16_t*)(ws + off); off += (size_t)3 * HKDIM * DH * 2;           // 0.75 MiB
    bf16_t* wo  = (bf16_t*)(ws + off); off += (size_t)DH * HKDIM * 2;               // 0.25 MiB
    bf16_t* kb  = (bf16_t*)(ws + off); off += (size_t)BATCH * NH * T_SEQ * DH * 2;  // 16 MiB
    bf16_t* qb  = (bf16_t*)(ws + off); off += (size_t)BATCH * NH * T_SEQ * DH * 2;  // 16 MiB
    bf16_t* vtb = (bf16_t*)(ws + off); off += (size_t)BATCH * NH * T_SEQ * DH * 2;  // 16 MiB
    bf16_t* ob  = (bf16_t*)(ws + off); off += (size_t)BATCH * T_SEQ * HKDIM * 2;    // 16 MiB

    convert_kernel<<<1536, 256, 0, stream>>>(x, Wk, Wq, Wv, Wo, xb, w3, wo);
    proj_kernel<<<dim3(64, 48), 256, 0, stream>>>(xb, w3, bk, bq, bv, kb, qb, vtb);
    attn_kernel<<<512, 256, 0, stream>>>(kb, qb, vtb, ob);
    outproj_kernel<<<512, 256, 0, stream>>>(ob, wo, bo, out);
}

// Round 10
// 110.620 us; speedup vs baseline: 1.8656x; 1.0887x over previous
//
#include <hip/hip_runtime.h>
#include <hip/hip_bf16.h>

typedef __bf16 bf16_t;
typedef __bf16 bf16x2_t __attribute__((ext_vector_type(2)));
typedef __bf16 bf16x4_t __attribute__((ext_vector_type(4)));
typedef __bf16 bf16x8 __attribute__((ext_vector_type(8)));
typedef float f32x4 __attribute__((ext_vector_type(4)));
typedef float f32x16 __attribute__((ext_vector_type(16)));
typedef unsigned int u32x2 __attribute__((ext_vector_type(2)));

#define T_SEQ 1024
#define BATCH 8
#define NH 8
#define DH 128
#define HKDIM 1024  // NH*DH

static __device__ __forceinline__ f32x4 mfma16(bf16x8 a, bf16x8 b, f32x4 c) {
    return __builtin_amdgcn_mfma_f32_16x16x32_bf16(a, b, c, 0, 0, 0);
}
static __device__ __forceinline__ f32x16 mfma32(bf16x8 a, bf16x8 b, f32x16 c) {
    return __builtin_amdgcn_mfma_f32_32x32x16_bf16(a, b, c, 0, 0, 0);
}

static __device__ __forceinline__ unsigned pk2(float a, float b) {
    bf16x2_t t;
    t[0] = (bf16_t)a;
    t[1] = (bf16_t)b;
    union { bf16x2_t v; unsigned u; } c;
    c.v = t;
    return c.u;
}

// v_permlane32_swap via builtin: r[0] = {a.lo, b.lo}, r[1] = {a.hi, b.hi}
static __device__ __forceinline__ void plswap(unsigned& a, unsigned& b) {
    u32x2 r = __builtin_amdgcn_permlane32_swap(a, b, false, false);
    a = r[0];
    b = r[1];
}

// value of x from lane^32 (pure VALU, no DS)
static __device__ __forceinline__ float swap_partner(float x) {
    u32x2 r = __builtin_amdgcn_permlane32_swap(__float_as_uint(x),
                                               __float_as_uint(x), false, false);
    return __uint_as_float((threadIdx.x & 32) ? r[0] : r[1]);
}

// ---------------------------------------------------------------------------
// Kernel 1: convert inputs to bf16 working layouts (float4-vectorized).
// ---------------------------------------------------------------------------
__global__ __launch_bounds__(256) void convert_kernel(
        const float* __restrict__ x,
        const float* __restrict__ Wk, const float* __restrict__ Wq,
        const float* __restrict__ Wv, const float* __restrict__ Wo,
        bf16_t* __restrict__ xb, bf16_t* __restrict__ w3,
        bf16_t* __restrict__ wo) {
    const int n1 = T_SEQ * BATCH * DH;        // 1048576
    const int n2 = n1 + 3 * HKDIM * DH;       // +393216
    const int n3 = n2 + DH * HKDIM;           // +131072
    const int i = (blockIdx.x * 256 + threadIdx.x) * 4;
    if (i >= n3) return;
    const float* src;
    bf16_t* dst;
    if (i < n1) {
        int d = i & 127, t = (i >> 7) & 1023, b = i >> 17;
        src = x + (t * BATCH + b) * DH + d;
        dst = xb + i;
    } else if (i < n2) {
        int j = i - n1;
        int p = j >> 17;
        const float* W = (p == 0) ? Wk : (p == 1 ? Wq : Wv);
        src = W + (j & 131071);
        dst = w3 + j;
    } else {
        int j = i - n2;
        src = Wo + j;
        dst = wo + j;
    }
    f32x4 v = *(const f32x4*)src;
    bf16x4_t o;
    o[0] = (bf16_t)v[0]; o[1] = (bf16_t)v[1];
    o[2] = (bf16_t)v[2]; o[3] = (bf16_t)v[3];
    *(bf16x4_t*)dst = o;
}

// ---------------------------------------------------------------------------
// Kernel 2: QKV projection (unchanged from r9).
// ---------------------------------------------------------------------------
__global__ __launch_bounds__(256) void proj_kernel(
        const bf16_t* __restrict__ xb, const bf16_t* __restrict__ w3,
        const float* __restrict__ bk, const float* __restrict__ bq,
        const float* __restrict__ bv,
        bf16_t* __restrict__ kbuf, bf16_t* __restrict__ qbuf,
        bf16_t* __restrict__ vtbuf) {
    const int lane = threadIdx.x & 63;
    const int wave = threadIdx.x >> 6;
    const int lr = lane & 15, lq = lane >> 4;
    const int rm_base = blockIdx.x * 128;
    const int cb0 = blockIdx.y * 64;
    const int p = cb0 >> 10;
    const int cw0 = cb0 & 1023;          // col within projection (0..960)
    const int h = cw0 >> 7;
    const int dbase = cw0 & 127;         // 0 or 64
    const bool isV = (p == 2);

    __shared__ bf16_t vL[64][136];       // [d_local][t_local 0..127], padded

    bf16x8 aF[2][4];
#pragma unroll
    for (int rg = 0; rg < 2; ++rg) {
        const int row = rm_base + rg * 64 + wave * 16 + lr;
#pragma unroll
        for (int kc = 0; kc < 4; ++kc)
            aF[rg][kc] = *(const bf16x8*)(xb + (size_t)row * DH + kc * 32 + lq * 8);
    }
    bf16x8 kf[16];
#pragma unroll
    for (int nc = 0; nc < 4; ++nc)
#pragma unroll
        for (int kc = 0; kc < 4; ++kc)
            kf[nc * 4 + kc] =
                *(const bf16x8*)(w3 + (size_t)(cb0 + nc * 16 + lr) * DH + kc * 32 + lq * 8);

    f32x4 acc[2][4];
#pragma unroll
    for (int rg = 0; rg < 2; ++rg)
#pragma unroll
        for (int nc = 0; nc < 4; ++nc) acc[rg][nc] = {0.f, 0.f, 0.f, 0.f};

    if (!isV) {
        // C[m = w-col][n = x-row]: lane n=lr (t-row), m = lq*4+r (d, consecutive)
#pragma unroll
        for (int rg = 0; rg < 2; ++rg)
#pragma unroll
            for (int nc = 0; nc < 4; ++nc)
#pragma unroll
                for (int kc = 0; kc < 4; ++kc)
                    acc[rg][nc] = mfma16(kf[nc * 4 + kc], aF[rg][kc], acc[rg][nc]);

        const float* bias_p = (p == 0) ? bk : bq;
        bf16_t* dst = (p == 0) ? kbuf : qbuf;
#pragma unroll
        for (int nc = 0; nc < 4; ++nc) {
            const f32x4 b4 = *(const f32x4*)(bias_p + cw0 + nc * 16 + lq * 4);
#pragma unroll
            for (int rg = 0; rg < 2; ++rg) {
                const int row = rm_base + rg * 64 + wave * 16 + lr;
                const int bb = row >> 10, tt = row & 1023;
                bf16x4_t o4;
#pragma unroll
                for (int r = 0; r < 4; ++r)
                    o4[r] = (bf16_t)(acc[rg][nc][r] + b4[r]);
                *(bf16x4_t*)(dst + ((size_t)(bb * NH + h) * T_SEQ + tt) * DH +
                             dbase + nc * 16 + lq * 4) = o4;
            }
        }
    } else {
        // C[m = x-row][n = w-col]: lane n=lr (d), m = lq*4+r (t)
#pragma unroll
        for (int rg = 0; rg < 2; ++rg)
#pragma unroll
            for (int nc = 0; nc < 4; ++nc)
#pragma unroll
                for (int kc = 0; kc < 4; ++kc)
                    acc[rg][nc] = mfma16(aF[rg][kc], kf[nc * 4 + kc], acc[rg][nc]);

#pragma unroll
        for (int nc = 0; nc < 4; ++nc) {
            const float bias = bv[cw0 + nc * 16 + lr];
#pragma unroll
            for (int rg = 0; rg < 2; ++rg)
#pragma unroll
                for (int r = 0; r < 4; ++r)
                    vL[nc * 16 + lr][rg * 64 + wave * 16 + lq * 4 + r] =
                        (bf16_t)(acc[rg][nc][r] + bias);
        }
        __syncthreads();
        // write out: 64 d-rows x 128 t, 64 B per thread, coalesced
        const int tid = threadIdx.x;
        const int dl = tid >> 2;             // 0..63
        const int toff = (tid & 3) * 32;     // elements within the 128-t row
        const int bb = blockIdx.x >> 3;
        const int t0 = (blockIdx.x & 7) * 128;
        const int dg = dbase + dl;
        bf16_t* dst = vtbuf + ((size_t)(bb * NH + h) * DH + dg) * T_SEQ + t0 + toff;
#pragma unroll
        for (int i = 0; i < 4; ++i)
            *(bf16x8*)(dst + i * 8) = *(const bf16x8*)&vL[dl][toff + i * 8];
    }
}

// ---------------------------------------------------------------------------
// Kernel 3: flash attention, 128-row i-tile per block, KVBLK=64 LDS staging
//   with async-stage prefetch (T14), CU-pairing grid remap.
//   Roles: Q' := K_proj (rows i), K' := Q_proj (cols j), V := V_proj.
//   Grid 512: bx<256 -> T=7-(bx>>6); bx>=256 -> T=(bx-256)>>6, bh=bx&63.
//   Round-robin CU assignment pairs T with 7-T (uniform 36 chunk-units/CU)
//   and co-locates same-bh blocks on one XCD (L2 reuse).
// ---------------------------------------------------------------------------
__global__ __launch_bounds__(256, 2) void attn_kernel(
        const bf16_t* __restrict__ kbuf, const bf16_t* __restrict__ qbuf,
        const bf16_t* __restrict__ vtb, bf16_t* __restrict__ obuf) {
    const int bx = blockIdx.x;
    const int T = (bx < 256) ? (7 - (bx >> 6)) : ((bx - 256) >> 6);
    const int bh = bx & 63;
    const int b = bh >> 3, h = bh & 7;
    const int wv = threadIdx.x >> 6;     // i-subtile 0..3
    const int lane = threadIdx.x & 63;
    const int li = lane & 31;
    const int hi = lane >> 5;
    const int i0 = T * 128 + wv * 32;    // wave's first row
    const int cmax = 4 * T + wv;         // last 32-chunk this wave computes
    const int nrounds = 2 * T + 2;       // 64-wide staging rounds

    const bf16_t* Qp = kbuf + (size_t)bh * T_SEQ * DH;  // rows i (key positions)
    const bf16_t* Kp = qbuf + (size_t)bh * T_SEQ * DH;  // cols j (query positions)
    const bf16_t* Vt = vtb + (size_t)bh * DH * T_SEQ;   // [d][t]

    __shared__ bf16_t kL[64][136];   // K super-chunk [j 0..63][d], 272B rows
    __shared__ bf16_t vL[128][72];   // V^T super-chunk [d][t 0..63], 144B rows

    // persistent Q B-fragments: lane: i=li, k = s*16 + hi*8 + e
    bf16x8 qf[8];
#pragma unroll
    for (int s = 0; s < 8; ++s)
        qf[s] = *(const bf16x8*)(Qp + (size_t)(i0 + li) * DH + s * 16 + hi * 8);

    f32x16 oacc[4];
#pragma unroll
    for (int c = 0; c < 4; ++c)
#pragma unroll
        for (int e = 0; e < 16; ++e) oacc[c][e] = 0.f;

    float m = 0.f, l = 0.f;
    const float C = 0.08838834764831845f * 1.4426950408889634f;  // scale*log2e

    // staging decomposition: 64B K + 64B V per thread per round
    const int tid = threadIdx.x;
    const int krow = tid >> 2;            // 0..63
    const int kcol = (tid & 3) * 32;      // 0,32,64,96
    const int vrow = tid >> 1;            // 0..127
    const int vcol = (tid & 1) * 32;      // 0,32
    const bf16_t* kgsrc = Kp + (size_t)krow * DH + kcol;
    const bf16_t* vgsrc = Vt + (size_t)vrow * T_SEQ + vcol;

    // prologue: load round 0 into registers
    bf16x8 kr[4], vr[4];
#pragma unroll
    for (int i = 0; i < 4; ++i) {
        kr[i] = *(const bf16x8*)(kgsrc + i * 8);
        vr[i] = *(const bf16x8*)(vgsrc + i * 8);
    }

    for (int rd = 0; rd < nrounds; ++rd) {
        __syncthreads();   // previous round's readers done
#pragma unroll
        for (int i = 0; i < 4; ++i) {
            *(bf16x8*)&kL[krow][kcol + i * 8] = kr[i];
            *(bf16x8*)&vL[vrow][vcol + i * 8] = vr[i];
        }
        // T14: issue next round's global loads now; they complete under
        // this round's compute and are consumed after the next barrier.
        if (rd + 1 < nrounds) {
            const bf16_t* kn = kgsrc + (size_t)(rd + 1) * 64 * DH;
            const bf16_t* vn = vgsrc + (size_t)(rd + 1) * 64;
#pragma unroll
            for (int i = 0; i < 4; ++i) {
                kr[i] = *(const bf16x8*)(kn + i * 8);
                vr[i] = *(const bf16x8*)(vn + i * 8);
            }
        }
        __syncthreads();   // LDS for this round ready

#pragma unroll
        for (int jj = 0; jj < 2; ++jj) {
            const int c32 = rd * 2 + jj;
            if (c32 > cmax) continue;

            // K fragments from LDS
            bf16x8 ka[8];
#pragma unroll
            for (int s = 0; s < 8; ++s)
                ka[s] = *(const bf16x8*)&kL[jj * 32 + li][s * 16 + hi * 8];

            // S^T = K' Q'^T : C[m=j][n=i]
            f32x16 sc;
#pragma unroll
            for (int e = 0; e < 16; ++e) sc[e] = 0.f;
            __builtin_amdgcn_s_setprio(1);
#pragma unroll
            for (int s = 0; s < 8; ++s) sc = mfma32(ka[s], qf[s], sc);
            __builtin_amdgcn_s_setprio(0);

            // scale (+ diagonal causal mask: j > i)
            f32x16 sv;
#pragma unroll
            for (int e = 0; e < 16; ++e) sv[e] = sc[e] * C;
            if (c32 == cmax) {
#pragma unroll
                for (int r = 0; r < 16; ++r) {
                    const int jrow = (r & 3) + 8 * (r >> 2) + 4 * hi;
                    if (jrow > li) sv[r] = -1e30f;
                }
            }

            // row max: in-lane tree + cross-half permlane (no DS)
            float pm = sv[0];
#pragma unroll
            for (int r = 1; r < 16; ++r) pm = fmaxf(pm, sv[r]);
            pm = fmaxf(pm, swap_partner(pm));

            // T13 defer-rescale (log2 domain, THR=8)
            if (!__all(pm <= m + 8.f)) {
                const float mn = fmaxf(m, pm);
                const float f = exp2f(m - mn);
                m = mn;
                l *= f;
#pragma unroll
                for (int cc = 0; cc < 4; ++cc)
#pragma unroll
                    for (int e = 0; e < 16; ++e) oacc[cc][e] *= f;
            }

            // P = 2^(sv - m), pack to bf16 pairs along j
            float ls = 0.f;
            unsigned Wp[8];
#pragma unroll
            for (int q = 0; q < 4; ++q) {
                const float p0 = exp2f(sv[4 * q + 0] - m);
                const float p1 = exp2f(sv[4 * q + 1] - m);
                const float p2 = exp2f(sv[4 * q + 2] - m);
                const float p3 = exp2f(sv[4 * q + 3] - m);
                ls += (p0 + p1) + (p2 + p3);
                Wp[2 * q] = pk2(p0, p1);
                Wp[2 * q + 1] = pk2(p2, p3);
            }
            l += ls;

            // redistribute P into B-fragments: 4 permlane32_swap (pure VALU)
            plswap(Wp[0], Wp[2]);
            plswap(Wp[1], Wp[3]);
            plswap(Wp[4], Wp[6]);
            plswap(Wp[5], Wp[7]);
            union { unsigned u[4]; bf16x8 v; } pb0, pb1;
            pb0.u[0] = Wp[0]; pb0.u[1] = Wp[1]; pb0.u[2] = Wp[2]; pb0.u[3] = Wp[3];
            pb1.u[0] = Wp[4]; pb1.u[1] = Wp[5]; pb1.u[2] = Wp[6]; pb1.u[3] = Wp[7];

            // V fragments from LDS; PV: O^T[d][i] += V^T[d][j] P[j][i]
            bf16x8 va[8];
#pragma unroll
            for (int n = 0; n < 4; ++n) {
                va[2 * n]     = *(const bf16x8*)&vL[li + 32 * n][jj * 32 + hi * 8];
                va[2 * n + 1] = *(const bf16x8*)&vL[li + 32 * n][jj * 32 + hi * 8 + 16];
            }
            __builtin_amdgcn_s_setprio(1);
            oacc[0] = mfma32(va[0], pb0.v, oacc[0]);
            oacc[0] = mfma32(va[1], pb1.v, oacc[0]);
            oacc[1] = mfma32(va[2], pb0.v, oacc[1]);
            oacc[1] = mfma32(va[3], pb1.v, oacc[1]);
            oacc[2] = mfma32(va[4], pb0.v, oacc[2]);
            oacc[2] = mfma32(va[5], pb1.v, oacc[2]);
            oacc[3] = mfma32(va[6], pb0.v, oacc[3]);
            oacc[3] = mfma32(va[7], pb1.v, oacc[3]);
            __builtin_amdgcn_s_setprio(0);
        }
    }

    // epilogue: each wave owns complete rows — normalize and store directly
    const float lfull = l + swap_partner(l);
    const float inv = 1.f / lfull;
    bf16_t* orow = obuf + ((size_t)b * T_SEQ + i0 + li) * HKDIM + h * DH;
#pragma unroll
    for (int c = 0; c < 4; ++c)
#pragma unroll
        for (int q = 0; q < 4; ++q) {
            bf16x4_t o4;
#pragma unroll
            for (int rr = 0; rr < 4; ++rr)
                o4[rr] = (bf16_t)(oacc[c][4 * q + rr] * inv);
            *(bf16x4_t*)(orow + c * 32 + q * 8 + 4 * hi) = o4;
        }
}

// ---------------------------------------------------------------------------
// Kernel 4: output projection, split-K over waves (unchanged from r9).
// ---------------------------------------------------------------------------
__global__ __launch_bounds__(256) void outproj_kernel(
        const bf16_t* __restrict__ obuf, const bf16_t* __restrict__ wo,
        const float* __restrict__ bo, float* __restrict__ out) {
    const int lane = threadIdx.x & 63, wave = threadIdx.x >> 6;
    const int lr = lane & 15, lq = lane >> 4;
    const int rm0 = blockIdx.x * 16;
    __shared__ float red[4][8][256];   // [wave][g][lane*4]

    f32x4 acc[8];
#pragma unroll
    for (int g = 0; g < 8; ++g) acc[g] = {0.f, 0.f, 0.f, 0.f};
#pragma unroll 2
    for (int k8 = 0; k8 < 8; ++k8) {
        const int kc = wave * 8 + k8;
        bf16x8 aF = *(const bf16x8*)(obuf + (size_t)(rm0 + lr) * HKDIM + kc * 32 + lq * 8);
#pragma unroll
        for (int g = 0; g < 8; ++g) {
            bf16x8 bF = *(const bf16x8*)(wo + (size_t)(g * 16 + lr) * HKDIM + kc * 32 + lq * 8);
            acc[g] = mfma16(aF, bF, acc[g]);
        }
    }
#pragma unroll
    for (int g = 0; g < 8; ++g)
        *(f32x4*)&red[wave][g][lane * 4] = acc[g];
    __syncthreads();
#pragma unroll
    for (int gi = 0; gi < 2; ++gi) {
        const int g = wave * 2 + gi;
        f32x4 s = *(const f32x4*)&red[0][g][lane * 4];
#pragma unroll
        for (int w = 1; w < 4; ++w) {
            f32x4 t = *(const f32x4*)&red[w][g][lane * 4];
            s[0] += t[0]; s[1] += t[1]; s[2] += t[2]; s[3] += t[3];
        }
        const int col = g * 16 + lr;
        const float bias = bo[col];
#pragma unroll
        for (int r = 0; r < 4; ++r) {
            const int row = rm0 + lq * 4 + r;
            const int bb = row >> 10, tt = row & 1023;
            out[((size_t)tt * BATCH + bb) * DH + col] = s[r] + bias;
        }
    }
}

// ---------------------------------------------------------------------------
extern "C" void kernel_launch(void* const* d_in, const int* in_sizes, int n_in,
                              void* d_out, int out_size, void* d_ws, size_t ws_size,
                              hipStream_t stream) {
    const float* x  = (const float*)d_in[0];
    const float* Wk = (const float*)d_in[1];
    const float* bk = (const float*)d_in[2];
    const float* Wq = (const float*)d_in[3];
    const float* bq = (const float*)d_in[4];
    const float* Wv = (const float*)d_in[5];
    const float* bv = (const float*)d_in[6];
    const float* Wo = (const float*)d_in[7];
    const float* bo = (const float*)d_in[8];
    float* out = (float*)d_out;

    char* ws = (char*)d_ws;
    size_t off = 0;
    bf16_t* xb  = (bf16_t*)(ws + off); off += (size_t)BATCH * T_SEQ * DH * 2;       // 2 MiB
    bf16_t* w3  = (bf16_t*)(ws + off); off += (size_t)3 * HKDIM * DH * 2;           // 0.75 MiB
    bf16_t* wo  = (bf16_t*)(ws + off); off += (size_t)DH * HKDIM * 2;               // 0.25 MiB
    bf16_t* kb  = (bf16_t*)(ws + off); off += (size_t)BATCH * NH * T_SEQ * DH * 2;  // 16 MiB
    bf16_t* qb  = (bf16_t*)(ws + off); off += (size_t)BATCH * NH * T_SEQ * DH * 2;  // 16 MiB
    bf16_t* vtb = (bf16_t*)(ws + off); off += (size_t)BATCH * NH * T_SEQ * DH * 2;  // 16 MiB
    bf16_t* ob  = (bf16_t*)(ws + off); off += (size_t)BATCH * T_SEQ * HKDIM * 2;    // 16 MiB

    convert_kernel<<<1536, 256, 0, stream>>>(x, Wk, Wq, Wv, Wo, xb, w3, wo);
    proj_kernel<<<dim3(64, 48), 256, 0, stream>>>(xb, w3, bk, bq, bv, kb, qb, vtb);
    attn_kernel<<<512, 256, 0, stream>>>(kb, qb, vtb, ob);
    outproj_kernel<<<512, 256, 0, stream>>>(ob, wo, bo, out);
}

// Round 11
// 107.768 us; speedup vs baseline: 1.9150x; 1.0265x over previous
//
#include <hip/hip_runtime.h>
#include <hip/hip_bf16.h>

typedef __bf16 bf16_t;
typedef __bf16 bf16x2_t __attribute__((ext_vector_type(2)));
typedef __bf16 bf16x4_t __attribute__((ext_vector_type(4)));
typedef __bf16 bf16x8 __attribute__((ext_vector_type(8)));
typedef float f32x4 __attribute__((ext_vector_type(4)));
typedef float f32x16 __attribute__((ext_vector_type(16)));
typedef unsigned int u32x2 __attribute__((ext_vector_type(2)));

#define T_SEQ 1024
#define BATCH 8
#define NH 8
#define DH 128
#define HKDIM 1024  // NH*DH

static __device__ __forceinline__ f32x4 mfma16(bf16x8 a, bf16x8 b, f32x4 c) {
    return __builtin_amdgcn_mfma_f32_16x16x32_bf16(a, b, c, 0, 0, 0);
}
static __device__ __forceinline__ f32x16 mfma32(bf16x8 a, bf16x8 b, f32x16 c) {
    return __builtin_amdgcn_mfma_f32_32x32x16_bf16(a, b, c, 0, 0, 0);
}

static __device__ __forceinline__ unsigned pk2(float a, float b) {
    bf16x2_t t;
    t[0] = (bf16_t)a;
    t[1] = (bf16_t)b;
    union { bf16x2_t v; unsigned u; } c;
    c.v = t;
    return c.u;
}

// v_permlane32_swap via builtin: r[0] = {a.lo, b.lo}, r[1] = {a.hi, b.hi}
static __device__ __forceinline__ void plswap(unsigned& a, unsigned& b) {
    u32x2 r = __builtin_amdgcn_permlane32_swap(a, b, false, false);
    a = r[0];
    b = r[1];
}

// value of x from lane^32 (pure VALU, no DS)
static __device__ __forceinline__ float swap_partner(float x) {
    u32x2 r = __builtin_amdgcn_permlane32_swap(__float_as_uint(x),
                                               __float_as_uint(x), false, false);
    return __uint_as_float((threadIdx.x & 32) ? r[0] : r[1]);
}

// ---------------------------------------------------------------------------
// Kernel 1: convert inputs to bf16 working layouts (float4-vectorized).
// ---------------------------------------------------------------------------
__global__ __launch_bounds__(256) void convert_kernel(
        const float* __restrict__ x,
        const float* __restrict__ Wk, const float* __restrict__ Wq,
        const float* __restrict__ Wv, const float* __restrict__ Wo,
        bf16_t* __restrict__ xb, bf16_t* __restrict__ w3,
        bf16_t* __restrict__ wo) {
    const int n1 = T_SEQ * BATCH * DH;        // 1048576
    const int n2 = n1 + 3 * HKDIM * DH;       // +393216
    const int n3 = n2 + DH * HKDIM;           // +131072
    const int i = (blockIdx.x * 256 + threadIdx.x) * 4;
    if (i >= n3) return;
    const float* src;
    bf16_t* dst;
    if (i < n1) {
        int d = i & 127, t = (i >> 7) & 1023, b = i >> 17;
        src = x + (t * BATCH + b) * DH + d;
        dst = xb + i;
    } else if (i < n2) {
        int j = i - n1;
        int p = j >> 17;
        const float* W = (p == 0) ? Wk : (p == 1 ? Wq : Wv);
        src = W + (j & 131071);
        dst = w3 + j;
    } else {
        int j = i - n2;
        src = Wo + j;
        dst = wo + j;
    }
    f32x4 v = *(const f32x4*)src;
    bf16x4_t o;
    o[0] = (bf16_t)v[0]; o[1] = (bf16_t)v[1];
    o[2] = (bf16_t)v[2]; o[3] = (bf16_t)v[3];
    *(bf16x4_t*)dst = o;
}

// ---------------------------------------------------------------------------
// Kernel 2: QKV projection, 128-row blocks. __launch_bounds__(256,2) lifts
//   the VGPR cap (r10 showed VGPR=80: the compiler serialized the operand
//   loads into ~32 sequential L2 round trips). Explicit 2-deep nc-pipeline:
//   load next 4 W-fragments while 8 MFMAs consume the current 4.
//   K/Q: swapped operand order -> 8-B full-sector stores. V: LDS transpose,
//   written [bh][d][t] as contiguous stores.
// ---------------------------------------------------------------------------
__global__ __launch_bounds__(256, 2) void proj_kernel(
        const bf16_t* __restrict__ xb, const bf16_t* __restrict__ w3,
        const float* __restrict__ bk, const float* __restrict__ bq,
        const float* __restrict__ bv,
        bf16_t* __restrict__ kbuf, bf16_t* __restrict__ qbuf,
        bf16_t* __restrict__ vtbuf) {
    const int lane = threadIdx.x & 63;
    const int wave = threadIdx.x >> 6;
    const int lr = lane & 15, lq = lane >> 4;
    const int rm_base = blockIdx.x * 128;
    const int cb0 = blockIdx.y * 64;
    const int p = cb0 >> 10;
    const int cw0 = cb0 & 1023;          // col within projection (0..960)
    const int h = cw0 >> 7;
    const int dbase = cw0 & 127;         // 0 or 64
    const bool isV = (p == 2);

    __shared__ bf16_t vL[64][136];       // [d_local][t_local 0..127], padded

    // A fragments: 8 loads, all in flight
    bf16x8 aF[2][4];
#pragma unroll
    for (int rg = 0; rg < 2; ++rg) {
        const int row = rm_base + rg * 64 + wave * 16 + lr;
#pragma unroll
        for (int kc = 0; kc < 4; ++kc)
            aF[rg][kc] = *(const bf16x8*)(xb + (size_t)row * DH + kc * 32 + lq * 8);
    }

    const bf16_t* wbase = w3 + (size_t)(cb0 + lr) * DH + lq * 8;
    bf16x8 kcur[4], knxt[4];
#pragma unroll
    for (int kc = 0; kc < 4; ++kc)
        kcur[kc] = *(const bf16x8*)(wbase + kc * 32);

    const float* bias_kq = (p == 0) ? bk : bq;
    bf16_t* dst = (p == 0) ? kbuf : qbuf;

#pragma unroll
    for (int nc = 0; nc < 4; ++nc) {
        // prefetch next nc's 4 W-fragments (completes under this nc's MFMAs)
        if (nc < 3) {
            const bf16_t* wn = wbase + (size_t)(nc + 1) * 16 * DH;
#pragma unroll
            for (int kc = 0; kc < 4; ++kc)
                knxt[kc] = *(const bf16x8*)(wn + kc * 32);
        }

        f32x4 acc[2] = {{0.f, 0.f, 0.f, 0.f}, {0.f, 0.f, 0.f, 0.f}};
        if (!isV) {
            // C[m = w-col][n = x-row]: lane n=lr (t-row), m = lq*4+r (d, consec.)
#pragma unroll
            for (int rg = 0; rg < 2; ++rg)
#pragma unroll
                for (int kc = 0; kc < 4; ++kc)
                    acc[rg] = mfma16(kcur[kc], aF[rg][kc], acc[rg]);

            const f32x4 b4 = *(const f32x4*)(bias_kq + cw0 + nc * 16 + lq * 4);
#pragma unroll
            for (int rg = 0; rg < 2; ++rg) {
                const int row = rm_base + rg * 64 + wave * 16 + lr;
                const int bb = row >> 10, tt = row & 1023;
                bf16x4_t o4;
#pragma unroll
                for (int r = 0; r < 4; ++r)
                    o4[r] = (bf16_t)(acc[rg][r] + b4[r]);
                *(bf16x4_t*)(dst + ((size_t)(bb * NH + h) * T_SEQ + tt) * DH +
                             dbase + nc * 16 + lq * 4) = o4;
            }
        } else {
            // C[m = x-row][n = w-col]: lane n=lr (d), m = lq*4+r (t)
#pragma unroll
            for (int rg = 0; rg < 2; ++rg)
#pragma unroll
                for (int kc = 0; kc < 4; ++kc)
                    acc[rg] = mfma16(aF[rg][kc], kcur[kc], acc[rg]);

            const float bias = bv[cw0 + nc * 16 + lr];
#pragma unroll
            for (int rg = 0; rg < 2; ++rg)
#pragma unroll
                for (int r = 0; r < 4; ++r)
                    vL[nc * 16 + lr][rg * 64 + wave * 16 + lq * 4 + r] =
                        (bf16_t)(acc[rg][r] + bias);
        }
        if (nc < 3) {
#pragma unroll
            for (int kc = 0; kc < 4; ++kc) kcur[kc] = knxt[kc];
        }
    }

    if (isV) {
        __syncthreads();
        // write out: 64 d-rows x 128 t, 64 B per thread, coalesced
        const int tid = threadIdx.x;
        const int dl = tid >> 2;             // 0..63
        const int toff = (tid & 3) * 32;     // elements within the 128-t row
        const int bb = blockIdx.x >> 3;
        const int t0 = (blockIdx.x & 7) * 128;
        const int dg = dbase + dl;
        bf16_t* dstv = vtbuf + ((size_t)(bb * NH + h) * DH + dg) * T_SEQ + t0 + toff;
#pragma unroll
        for (int i = 0; i < 4; ++i)
            *(bf16x8*)(dstv + i * 8) = *(const bf16x8*)&vL[dl][toff + i * 8];
    }
}

// ---------------------------------------------------------------------------
// Kernel 3: flash attention, 128-row i-tile per block, KVBLK=64 LDS staging
//   with async-stage prefetch (T14), CU-pairing grid remap (unchanged r10).
// ---------------------------------------------------------------------------
__global__ __launch_bounds__(256, 2) void attn_kernel(
        const bf16_t* __restrict__ kbuf, const bf16_t* __restrict__ qbuf,
        const bf16_t* __restrict__ vtb, bf16_t* __restrict__ obuf) {
    const int bx = blockIdx.x;
    const int T = (bx < 256) ? (7 - (bx >> 6)) : ((bx - 256) >> 6);
    const int bh = bx & 63;
    const int b = bh >> 3, h = bh & 7;
    const int wv = threadIdx.x >> 6;     // i-subtile 0..3
    const int lane = threadIdx.x & 63;
    const int li = lane & 31;
    const int hi = lane >> 5;
    const int i0 = T * 128 + wv * 32;    // wave's first row
    const int cmax = 4 * T + wv;         // last 32-chunk this wave computes
    const int nrounds = 2 * T + 2;       // 64-wide staging rounds

    const bf16_t* Qp = kbuf + (size_t)bh * T_SEQ * DH;  // rows i (key positions)
    const bf16_t* Kp = qbuf + (size_t)bh * T_SEQ * DH;  // cols j (query positions)
    const bf16_t* Vt = vtb + (size_t)bh * DH * T_SEQ;   // [d][t]

    __shared__ bf16_t kL[64][136];   // K super-chunk [j 0..63][d], 272B rows
    __shared__ bf16_t vL[128][72];   // V^T super-chunk [d][t 0..63], 144B rows

    // persistent Q B-fragments: lane: i=li, k = s*16 + hi*8 + e
    bf16x8 qf[8];
#pragma unroll
    for (int s = 0; s < 8; ++s)
        qf[s] = *(const bf16x8*)(Qp + (size_t)(i0 + li) * DH + s * 16 + hi * 8);

    f32x16 oacc[4];
#pragma unroll
    for (int c = 0; c < 4; ++c)
#pragma unroll
        for (int e = 0; e < 16; ++e) oacc[c][e] = 0.f;

    float m = 0.f, l = 0.f;
    const float C = 0.08838834764831845f * 1.4426950408889634f;  // scale*log2e

    // staging decomposition: 64B K + 64B V per thread per round
    const int tid = threadIdx.x;
    const int krow = tid >> 2;            // 0..63
    const int kcol = (tid & 3) * 32;      // 0,32,64,96
    const int vrow = tid >> 1;            // 0..127
    const int vcol = (tid & 1) * 32;      // 0,32
    const bf16_t* kgsrc = Kp + (size_t)krow * DH + kcol;
    const bf16_t* vgsrc = Vt + (size_t)vrow * T_SEQ + vcol;

    // prologue: load round 0 into registers
    bf16x8 kr[4], vr[4];
#pragma unroll
    for (int i = 0; i < 4; ++i) {
        kr[i] = *(const bf16x8*)(kgsrc + i * 8);
        vr[i] = *(const bf16x8*)(vgsrc + i * 8);
    }

    for (int rd = 0; rd < nrounds; ++rd) {
        __syncthreads();   // previous round's readers done
#pragma unroll
        for (int i = 0; i < 4; ++i) {
            *(bf16x8*)&kL[krow][kcol + i * 8] = kr[i];
            *(bf16x8*)&vL[vrow][vcol + i * 8] = vr[i];
        }
        // T14: issue next round's global loads now; they complete under
        // this round's compute and are consumed after the next barrier.
        if (rd + 1 < nrounds) {
            const bf16_t* kn = kgsrc + (size_t)(rd + 1) * 64 * DH;
            const bf16_t* vn = vgsrc + (size_t)(rd + 1) * 64;
#pragma unroll
            for (int i = 0; i < 4; ++i) {
                kr[i] = *(const bf16x8*)(kn + i * 8);
                vr[i] = *(const bf16x8*)(vn + i * 8);
            }
        }
        __syncthreads();   // LDS for this round ready

#pragma unroll
        for (int jj = 0; jj < 2; ++jj) {
            const int c32 = rd * 2 + jj;
            if (c32 > cmax) continue;

            // K fragments from LDS
            bf16x8 ka[8];
#pragma unroll
            for (int s = 0; s < 8; ++s)
                ka[s] = *(const bf16x8*)&kL[jj * 32 + li][s * 16 + hi * 8];

            // S^T = K' Q'^T : C[m=j][n=i]
            f32x16 sc;
#pragma unroll
            for (int e = 0; e < 16; ++e) sc[e] = 0.f;
            __builtin_amdgcn_s_setprio(1);
#pragma unroll
            for (int s = 0; s < 8; ++s) sc = mfma32(ka[s], qf[s], sc);
            __builtin_amdgcn_s_setprio(0);

            // scale (+ diagonal causal mask: j > i)
            f32x16 sv;
#pragma unroll
            for (int e = 0; e < 16; ++e) sv[e] = sc[e] * C;
            if (c32 == cmax) {
#pragma unroll
                for (int r = 0; r < 16; ++r) {
                    const int jrow = (r & 3) + 8 * (r >> 2) + 4 * hi;
                    if (jrow > li) sv[r] = -1e30f;
                }
            }

            // row max: in-lane tree + cross-half permlane (no DS)
            float pm = sv[0];
#pragma unroll
            for (int r = 1; r < 16; ++r) pm = fmaxf(pm, sv[r]);
            pm = fmaxf(pm, swap_partner(pm));

            // T13 defer-rescale (log2 domain, THR=8)
            if (!__all(pm <= m + 8.f)) {
                const float mn = fmaxf(m, pm);
                const float f = exp2f(m - mn);
                m = mn;
                l *= f;
#pragma unroll
                for (int cc = 0; cc < 4; ++cc)
#pragma unroll
                    for (int e = 0; e < 16; ++e) oacc[cc][e] *= f;
            }

            // P = 2^(sv - m), pack to bf16 pairs along j
            float ls = 0.f;
            unsigned Wp[8];
#pragma unroll
            for (int q = 0; q < 4; ++q) {
                const float p0 = exp2f(sv[4 * q + 0] - m);
                const float p1 = exp2f(sv[4 * q + 1] - m);
                const float p2 = exp2f(sv[4 * q + 2] - m);
                const float p3 = exp2f(sv[4 * q + 3] - m);
                ls += (p0 + p1) + (p2 + p3);
                Wp[2 * q] = pk2(p0, p1);
                Wp[2 * q + 1] = pk2(p2, p3);
            }
            l += ls;

            // redistribute P into B-fragments: 4 permlane32_swap (pure VALU)
            plswap(Wp[0], Wp[2]);
            plswap(Wp[1], Wp[3]);
            plswap(Wp[4], Wp[6]);
            plswap(Wp[5], Wp[7]);
            union { unsigned u[4]; bf16x8 v; } pb0, pb1;
            pb0.u[0] = Wp[0]; pb0.u[1] = Wp[1]; pb0.u[2] = Wp[2]; pb0.u[3] = Wp[3];
            pb1.u[0] = Wp[4]; pb1.u[1] = Wp[5]; pb1.u[2] = Wp[6]; pb1.u[3] = Wp[7];

            // V fragments from LDS; PV: O^T[d][i] += V^T[d][j] P[j][i]
            bf16x8 va[8];
#pragma unroll
            for (int n = 0; n < 4; ++n) {
                va[2 * n]     = *(const bf16x8*)&vL[li + 32 * n][jj * 32 + hi * 8];
                va[2 * n + 1] = *(const bf16x8*)&vL[li + 32 * n][jj * 32 + hi * 8 + 16];
            }
            __builtin_amdgcn_s_setprio(1);
            oacc[0] = mfma32(va[0], pb0.v, oacc[0]);
            oacc[0] = mfma32(va[1], pb1.v, oacc[0]);
            oacc[1] = mfma32(va[2], pb0.v, oacc[1]);
            oacc[1] = mfma32(va[3], pb1.v, oacc[1]);
            oacc[2] = mfma32(va[4], pb0.v, oacc[2]);
            oacc[2] = mfma32(va[5], pb1.v, oacc[2]);
            oacc[3] = mfma32(va[6], pb0.v, oacc[3]);
            oacc[3] = mfma32(va[7], pb1.v, oacc[3]);
            __builtin_amdgcn_s_setprio(0);
        }
    }

    // epilogue: each wave owns complete rows — normalize and store directly
    const float lfull = l + swap_partner(l);
    const float inv = 1.f / lfull;
    bf16_t* orow = obuf + ((size_t)b * T_SEQ + i0 + li) * HKDIM + h * DH;
#pragma unroll
    for (int c = 0; c < 4; ++c)
#pragma unroll
        for (int q = 0; q < 4; ++q) {
            bf16x4_t o4;
#pragma unroll
            for (int rr = 0; rr < 4; ++rr)
                o4[rr] = (bf16_t)(oacc[c][4 * q + rr] * inv);
            *(bf16x4_t*)(orow + c * 32 + q * 8 + 4 * hi) = o4;
        }
}

// ---------------------------------------------------------------------------
// Kernel 4: output projection, split-K over waves (unchanged).
// ---------------------------------------------------------------------------
__global__ __launch_bounds__(256) void outproj_kernel(
        const bf16_t* __restrict__ obuf, const bf16_t* __restrict__ wo,
        const float* __restrict__ bo, float* __restrict__ out) {
    const int lane = threadIdx.x & 63, wave = threadIdx.x >> 6;
    const int lr = lane & 15, lq = lane >> 4;
    const int rm0 = blockIdx.x * 16;
    __shared__ float red[4][8][256];   // [wave][g][lane*4]

    f32x4 acc[8];
#pragma unroll
    for (int g = 0; g < 8; ++g) acc[g] = {0.f, 0.f, 0.f, 0.f};
#pragma unroll 2
    for (int k8 = 0; k8 < 8; ++k8) {
        const int kc = wave * 8 + k8;
        bf16x8 aF = *(const bf16x8*)(obuf + (size_t)(rm0 + lr) * HKDIM + kc * 32 + lq * 8);
#pragma unroll
        for (int g = 0; g < 8; ++g) {
            bf16x8 bF = *(const bf16x8*)(wo + (size_t)(g * 16 + lr) * HKDIM + kc * 32 + lq * 8);
            acc[g] = mfma16(aF, bF, acc[g]);
        }
    }
#pragma unroll
    for (int g = 0; g < 8; ++g)
        *(f32x4*)&red[wave][g][lane * 4] = acc[g];
    __syncthreads();
#pragma unroll
    for (int gi = 0; gi < 2; ++gi) {
        const int g = wave * 2 + gi;
        f32x4 s = *(const f32x4*)&red[0][g][lane * 4];
#pragma unroll
        for (int w = 1; w < 4; ++w) {
            f32x4 t = *(const f32x4*)&red[w][g][lane * 4];
            s[0] += t[0]; s[1] += t[1]; s[2] += t[2]; s[3] += t[3];
        }
        const int col = g * 16 + lr;
        const float bias = bo[col];
#pragma unroll
        for (int r = 0; r < 4; ++r) {
            const int row = rm0 + lq * 4 + r;
            const int bb = row >> 10, tt = row & 1023;
            out[((size_t)tt * BATCH + bb) * DH + col] = s[r] + bias;
        }
    }
}

// ---------------------------------------------------------------------------
extern "C" void kernel_launch(void* const* d_in, const int* in_sizes, int n_in,
                              void* d_out, int out_size, void* d_ws, size_t ws_size,
                              hipStream_t stream) {
    const float* x  = (const float*)d_in[0];
    const float* Wk = (const float*)d_in[1];
    const float* bk = (const float*)d_in[2];
    const float* Wq = (const float*)d_in[3];
    const float* bq = (const float*)d_in[4];
    const float* Wv = (const float*)d_in[5];
    const float* bv = (const float*)d_in[6];
    const float* Wo = (const float*)d_in[7];
    const float* bo = (const float*)d_in[8];
    float* out = (float*)d_out;

    char* ws = (char*)d_ws;
    size_t off = 0;
    bf16_t* xb  = (bf16_t*)(ws + off); off += (size_t)BATCH * T_SEQ * DH * 2;       // 2 MiB
    bf16_t* w3  = (bf16_t*)(ws + off); off += (size_t)3 * HKDIM * DH * 2;           // 0.75 MiB
    bf16_t* wo  = (bf16_t*)(ws + off); off += (size_t)DH * HKDIM * 2;               // 0.25 MiB
    bf16_t* kb  = (bf16_t*)(ws + off); off += (size_t)BATCH * NH * T_SEQ * DH * 2;  // 16 MiB
    bf16_t* qb  = (bf16_t*)(ws + off); off += (size_t)BATCH * NH * T_SEQ * DH * 2;  // 16 MiB
    bf16_t* vtb = (bf16_t*)(ws + off); off += (size_t)BATCH * NH * T_SEQ * DH * 2;  // 16 MiB
    bf16_t* ob  = (bf16_t*)(ws + off); off += (size_t)BATCH * T_SEQ * HKDIM * 2;    // 16 MiB

    convert_kernel<<<1536, 256, 0, stream>>>(x, Wk, Wq, Wv, Wo, xb, w3, wo);
    proj_kernel<<<dim3(64, 48), 256, 0, stream>>>(xb, w3, bk, bq, bv, kb, qb, vtb);
    attn_kernel<<<512, 256, 0, stream>>>(kb, qb, vtb, ob);
    outproj_kernel<<<512, 256, 0, stream>>>(ob, wo, bo, out);
}

// Round 12
// 107.225 us; speedup vs baseline: 1.9247x; 1.0051x over previous
//
#include <hip/hip_runtime.h>
#include <hip/hip_bf16.h>

typedef __bf16 bf16_t;
typedef __bf16 bf16x2_t __attribute__((ext_vector_type(2)));
typedef __bf16 bf16x4_t __attribute__((ext_vector_type(4)));
typedef __bf16 bf16x8 __attribute__((ext_vector_type(8)));
typedef float f32x4 __attribute__((ext_vector_type(4)));
typedef float f32x16 __attribute__((ext_vector_type(16)));
typedef unsigned int u32x2 __attribute__((ext_vector_type(2)));

#define T_SEQ 1024
#define BATCH 8
#define NH 8
#define DH 128
#define HKDIM 1024  // NH*DH

static __device__ __forceinline__ f32x4 mfma16(bf16x8 a, bf16x8 b, f32x4 c) {
    return __builtin_amdgcn_mfma_f32_16x16x32_bf16(a, b, c, 0, 0, 0);
}
static __device__ __forceinline__ f32x16 mfma32(bf16x8 a, bf16x8 b, f32x16 c) {
    return __builtin_amdgcn_mfma_f32_32x32x16_bf16(a, b, c, 0, 0, 0);
}

static __device__ __forceinline__ unsigned pk2(float a, float b) {
    bf16x2_t t;
    t[0] = (bf16_t)a;
    t[1] = (bf16_t)b;
    union { bf16x2_t v; unsigned u; } c;
    c.v = t;
    return c.u;
}

// v_permlane32_swap via builtin: r[0] = {a.lo, b.lo}, r[1] = {a.hi, b.hi}
static __device__ __forceinline__ void plswap(unsigned& a, unsigned& b) {
    u32x2 r = __builtin_amdgcn_permlane32_swap(a, b, false, false);
    a = r[0];
    b = r[1];
}

// value of x from lane^32 (pure VALU, no DS)
static __device__ __forceinline__ float swap_partner(float x) {
    u32x2 r = __builtin_amdgcn_permlane32_swap(__float_as_uint(x),
                                               __float_as_uint(x), false, false);
    return __uint_as_float((threadIdx.x & 32) ? r[0] : r[1]);
}

// ---------------------------------------------------------------------------
// Kernel 1: convert inputs to bf16 working layouts (float4-vectorized).
// ---------------------------------------------------------------------------
__global__ __launch_bounds__(256) void convert_kernel(
        const float* __restrict__ x,
        const float* __restrict__ Wk, const float* __restrict__ Wq,
        const float* __restrict__ Wv, const float* __restrict__ Wo,
        bf16_t* __restrict__ xb, bf16_t* __restrict__ w3,
        bf16_t* __restrict__ wo) {
    const int n1 = T_SEQ * BATCH * DH;        // 1048576
    const int n2 = n1 + 3 * HKDIM * DH;       // +393216
    const int n3 = n2 + DH * HKDIM;           // +131072
    const int i = (blockIdx.x * 256 + threadIdx.x) * 4;
    if (i >= n3) return;
    const float* src;
    bf16_t* dst;
    if (i < n1) {
        int d = i & 127, t = (i >> 7) & 1023, b = i >> 17;
        src = x + (t * BATCH + b) * DH + d;
        dst = xb + i;
    } else if (i < n2) {
        int j = i - n1;
        int p = j >> 17;
        const float* W = (p == 0) ? Wk : (p == 1 ? Wq : Wv);
        src = W + (j & 131071);
        dst = w3 + j;
    } else {
        int j = i - n2;
        src = Wo + j;
        dst = wo + j;
    }
    f32x4 v = *(const f32x4*)src;
    bf16x4_t o;
    o[0] = (bf16_t)v[0]; o[1] = (bf16_t)v[1];
    o[2] = (bf16_t)v[2]; o[3] = (bf16_t)v[3];
    *(bf16x4_t*)dst = o;
}

// ---------------------------------------------------------------------------
// Kernel 2: QKV projection, 128-row blocks. ALL outputs now route through a
//   17KB LDS tile and leave as 16B/lane stores with 8 consecutive lanes
//   covering a full 128B row-half: every 64B line fully written by one
//   wave-instruction (r8->r11 data showed duration tracks write-transaction
//   count; 8B stores left half-lines -> 2x the transactions).
//   K/Q: swapped operand order (W as A). V: LDS transpose to [bh][d][t].
// ---------------------------------------------------------------------------
__global__ __launch_bounds__(256) void proj_kernel(
        const bf16_t* __restrict__ xb, const bf16_t* __restrict__ w3,
        const float* __restrict__ bk, const float* __restrict__ bq,
        const float* __restrict__ bv,
        bf16_t* __restrict__ kbuf, bf16_t* __restrict__ qbuf,
        bf16_t* __restrict__ vtbuf) {
    const int lane = threadIdx.x & 63;
    const int wave = threadIdx.x >> 6;
    const int lr = lane & 15, lq = lane >> 4;
    const int rm_base = blockIdx.x * 128;
    const int cb0 = blockIdx.y * 64;
    const int p = cb0 >> 10;
    const int cw0 = cb0 & 1023;          // col within projection (0..960)
    const int h = cw0 >> 7;
    const int dbase = cw0 & 127;         // 0 or 64
    const bool isV = (p == 2);

    __shared__ bf16_t sL[17408 / 2];     // union: aL[128][68] / vL[64][136]

    // A fragments: 8 loads, all in flight
    bf16x8 aF[2][4];
#pragma unroll
    for (int rg = 0; rg < 2; ++rg) {
        const int row = rm_base + rg * 64 + wave * 16 + lr;
#pragma unroll
        for (int kc = 0; kc < 4; ++kc)
            aF[rg][kc] = *(const bf16x8*)(xb + (size_t)row * DH + kc * 32 + lq * 8);
    }

    const bf16_t* wbase = w3 + (size_t)(cb0 + lr) * DH + lq * 8;
    bf16x8 kcur[4], knxt[4];
#pragma unroll
    for (int kc = 0; kc < 4; ++kc)
        kcur[kc] = *(const bf16x8*)(wbase + kc * 32);

    const float* bias_kq = (p == 0) ? bk : bq;
    bf16_t* dst = (p == 0) ? kbuf : qbuf;

    bf16_t (*aL)[68] = (bf16_t(*)[68])sL;
    bf16_t (*vL)[136] = (bf16_t(*)[136])sL;

#pragma unroll
    for (int nc = 0; nc < 4; ++nc) {
        // prefetch next nc's 4 W-fragments (completes under this nc's MFMAs)
        if (nc < 3) {
            const bf16_t* wn = wbase + (size_t)(nc + 1) * 16 * DH;
#pragma unroll
            for (int kc = 0; kc < 4; ++kc)
                knxt[kc] = *(const bf16x8*)(wn + kc * 32);
        }

        f32x4 acc[2] = {{0.f, 0.f, 0.f, 0.f}, {0.f, 0.f, 0.f, 0.f}};
        if (!isV) {
            // C[m = w-col][n = x-row]: lane n=lr (t-row), m = lq*4+r (d, consec.)
#pragma unroll
            for (int rg = 0; rg < 2; ++rg)
#pragma unroll
                for (int kc = 0; kc < 4; ++kc)
                    acc[rg] = mfma16(kcur[kc], aF[rg][kc], acc[rg]);

            const f32x4 b4 = *(const f32x4*)(bias_kq + cw0 + nc * 16 + lq * 4);
#pragma unroll
            for (int rg = 0; rg < 2; ++rg) {
                bf16x4_t o4;
#pragma unroll
                for (int r = 0; r < 4; ++r)
                    o4[r] = (bf16_t)(acc[rg][r] + b4[r]);
                *(bf16x4_t*)&aL[rg * 64 + wave * 16 + lr][nc * 16 + lq * 4] = o4;
            }
        } else {
            // C[m = x-row][n = w-col]: lane n=lr (d), m = lq*4+r (t)
#pragma unroll
            for (int rg = 0; rg < 2; ++rg)
#pragma unroll
                for (int kc = 0; kc < 4; ++kc)
                    acc[rg] = mfma16(aF[rg][kc], kcur[kc], acc[rg]);

            const float bias = bv[cw0 + nc * 16 + lr];
#pragma unroll
            for (int rg = 0; rg < 2; ++rg)
#pragma unroll
                for (int r = 0; r < 4; ++r)
                    vL[nc * 16 + lr][rg * 64 + wave * 16 + lq * 4 + r] =
                        (bf16_t)(acc[rg][r] + bias);
        }
        if (nc < 3) {
#pragma unroll
            for (int kc = 0; kc < 4; ++kc) kcur[kc] = knxt[kc];
        }
    }

    __syncthreads();
    const int tid = threadIdx.x;
    if (!isV) {
        // readout: 4 passes x 32 t-rows; 8 lanes cover one row's 128B half.
        const int tr = tid >> 3;            // 0..31
        const int d16 = tid & 7;            // 16B chunk within 64-d half
#pragma unroll
        for (int ps = 0; ps < 4; ++ps) {
            const int t_local = ps * 32 + tr;
            const int row = rm_base + t_local;
            const int bb = row >> 10, tt = row & 1023;
            bf16x8 v = *(const bf16x8*)&aL[t_local][d16 * 8];
            *(bf16x8*)(dst + ((size_t)(bb * NH + h) * T_SEQ + tt) * DH +
                       dbase + d16 * 8) = v;
        }
    } else {
        // write out: 64 d-rows x 128 t, 64 B per thread, coalesced
        const int dl = tid >> 2;             // 0..63
        const int toff = (tid & 3) * 32;     // elements within the 128-t row
        const int bb = blockIdx.x >> 3;
        const int t0 = (blockIdx.x & 7) * 128;
        const int dg = dbase + dl;
        bf16_t* dstv = vtbuf + ((size_t)(bb * NH + h) * DH + dg) * T_SEQ + t0 + toff;
#pragma unroll
        for (int i = 0; i < 4; ++i)
            *(bf16x8*)(dstv + i * 8) = *(const bf16x8*)&vL[dl][toff + i * 8];
    }
}

// ---------------------------------------------------------------------------
// Kernel 3: flash attention, 128-row i-tile per block, KVBLK=64 LDS staging
//   with async-stage prefetch (T14), CU-pairing grid remap (unchanged).
// ---------------------------------------------------------------------------
__global__ __launch_bounds__(256, 2) void attn_kernel(
        const bf16_t* __restrict__ kbuf, const bf16_t* __restrict__ qbuf,
        const bf16_t* __restrict__ vtb, bf16_t* __restrict__ obuf) {
    const int bx = blockIdx.x;
    const int T = (bx < 256) ? (7 - (bx >> 6)) : ((bx - 256) >> 6);
    const int bh = bx & 63;
    const int b = bh >> 3, h = bh & 7;
    const int wv = threadIdx.x >> 6;     // i-subtile 0..3
    const int lane = threadIdx.x & 63;
    const int li = lane & 31;
    const int hi = lane >> 5;
    const int i0 = T * 128 + wv * 32;    // wave's first row
    const int cmax = 4 * T + wv;         // last 32-chunk this wave computes
    const int nrounds = 2 * T + 2;       // 64-wide staging rounds

    const bf16_t* Qp = kbuf + (size_t)bh * T_SEQ * DH;  // rows i (key positions)
    const bf16_t* Kp = qbuf + (size_t)bh * T_SEQ * DH;  // cols j (query positions)
    const bf16_t* Vt = vtb + (size_t)bh * DH * T_SEQ;   // [d][t]

    __shared__ bf16_t kL[64][136];   // K super-chunk [j 0..63][d], 272B rows
    __shared__ bf16_t vL[128][72];   // V^T super-chunk [d][t 0..63], 144B rows

    // persistent Q B-fragments: lane: i=li, k = s*16 + hi*8 + e
    bf16x8 qf[8];
#pragma unroll
    for (int s = 0; s < 8; ++s)
        qf[s] = *(const bf16x8*)(Qp + (size_t)(i0 + li) * DH + s * 16 + hi * 8);

    f32x16 oacc[4];
#pragma unroll
    for (int c = 0; c < 4; ++c)
#pragma unroll
        for (int e = 0; e < 16; ++e) oacc[c][e] = 0.f;

    float m = 0.f, l = 0.f;
    const float C = 0.08838834764831845f * 1.4426950408889634f;  // scale*log2e

    // staging decomposition: 64B K + 64B V per thread per round
    const int tid = threadIdx.x;
    const int krow = tid >> 2;            // 0..63
    const int kcol = (tid & 3) * 32;      // 0,32,64,96
    const int vrow = tid >> 1;            // 0..127
    const int vcol = (tid & 1) * 32;      // 0,32
    const bf16_t* kgsrc = Kp + (size_t)krow * DH + kcol;
    const bf16_t* vgsrc = Vt + (size_t)vrow * T_SEQ + vcol;

    // prologue: load round 0 into registers
    bf16x8 kr[4], vr[4];
#pragma unroll
    for (int i = 0; i < 4; ++i) {
        kr[i] = *(const bf16x8*)(kgsrc + i * 8);
        vr[i] = *(const bf16x8*)(vgsrc + i * 8);
    }

    for (int rd = 0; rd < nrounds; ++rd) {
        __syncthreads();   // previous round's readers done
#pragma unroll
        for (int i = 0; i < 4; ++i) {
            *(bf16x8*)&kL[krow][kcol + i * 8] = kr[i];
            *(bf16x8*)&vL[vrow][vcol + i * 8] = vr[i];
        }
        // T14: issue next round's global loads now; they complete under
        // this round's compute and are consumed after the next barrier.
        if (rd + 1 < nrounds) {
            const bf16_t* kn = kgsrc + (size_t)(rd + 1) * 64 * DH;
            const bf16_t* vn = vgsrc + (size_t)(rd + 1) * 64;
#pragma unroll
            for (int i = 0; i < 4; ++i) {
                kr[i] = *(const bf16x8*)(kn + i * 8);
                vr[i] = *(const bf16x8*)(vn + i * 8);
            }
        }
        __syncthreads();   // LDS for this round ready

#pragma unroll
        for (int jj = 0; jj < 2; ++jj) {
            const int c32 = rd * 2 + jj;
            if (c32 > cmax) continue;

            // K fragments from LDS
            bf16x8 ka[8];
#pragma unroll
            for (int s = 0; s < 8; ++s)
                ka[s] = *(const bf16x8*)&kL[jj * 32 + li][s * 16 + hi * 8];

            // S^T = K' Q'^T : C[m=j][n=i]
            f32x16 sc;
#pragma unroll
            for (int e = 0; e < 16; ++e) sc[e] = 0.f;
            __builtin_amdgcn_s_setprio(1);
#pragma unroll
            for (int s = 0; s < 8; ++s) sc = mfma32(ka[s], qf[s], sc);
            __builtin_amdgcn_s_setprio(0);

            // scale (+ diagonal causal mask: j > i)
            f32x16 sv;
#pragma unroll
            for (int e = 0; e < 16; ++e) sv[e] = sc[e] * C;
            if (c32 == cmax) {
#pragma unroll
                for (int r = 0; r < 16; ++r) {
                    const int jrow = (r & 3) + 8 * (r >> 2) + 4 * hi;
                    if (jrow > li) sv[r] = -1e30f;
                }
            }

            // row max: in-lane tree + cross-half permlane (no DS)
            float pm = sv[0];
#pragma unroll
            for (int r = 1; r < 16; ++r) pm = fmaxf(pm, sv[r]);
            pm = fmaxf(pm, swap_partner(pm));

            // T13 defer-rescale (log2 domain, THR=8)
            if (!__all(pm <= m + 8.f)) {
                const float mn = fmaxf(m, pm);
                const float f = exp2f(m - mn);
                m = mn;
                l *= f;
#pragma unroll
                for (int cc = 0; cc < 4; ++cc)
#pragma unroll
                    for (int e = 0; e < 16; ++e) oacc[cc][e] *= f;
            }

            // P = 2^(sv - m), pack to bf16 pairs along j
            float ls = 0.f;
            unsigned Wp[8];
#pragma unroll
            for (int q = 0; q < 4; ++q) {
                const float p0 = exp2f(sv[4 * q + 0] - m);
                const float p1 = exp2f(sv[4 * q + 1] - m);
                const float p2 = exp2f(sv[4 * q + 2] - m);
                const float p3 = exp2f(sv[4 * q + 3] - m);
                ls += (p0 + p1) + (p2 + p3);
                Wp[2 * q] = pk2(p0, p1);
                Wp[2 * q + 1] = pk2(p2, p3);
            }
            l += ls;

            // redistribute P into B-fragments: 4 permlane32_swap (pure VALU)
            plswap(Wp[0], Wp[2]);
            plswap(Wp[1], Wp[3]);
            plswap(Wp[4], Wp[6]);
            plswap(Wp[5], Wp[7]);
            union { unsigned u[4]; bf16x8 v; } pb0, pb1;
            pb0.u[0] = Wp[0]; pb0.u[1] = Wp[1]; pb0.u[2] = Wp[2]; pb0.u[3] = Wp[3];
            pb1.u[0] = Wp[4]; pb1.u[1] = Wp[5]; pb1.u[2] = Wp[6]; pb1.u[3] = Wp[7];

            // V fragments from LDS; PV: O^T[d][i] += V^T[d][j] P[j][i]
            bf16x8 va[8];
#pragma unroll
            for (int n = 0; n < 4; ++n) {
                va[2 * n]     = *(const bf16x8*)&vL[li + 32 * n][jj * 32 + hi * 8];
                va[2 * n + 1] = *(const bf16x8*)&vL[li + 32 * n][jj * 32 + hi * 8 + 16];
            }
            __builtin_amdgcn_s_setprio(1);
            oacc[0] = mfma32(va[0], pb0.v, oacc[0]);
            oacc[0] = mfma32(va[1], pb1.v, oacc[0]);
            oacc[1] = mfma32(va[2], pb0.v, oacc[1]);
            oacc[1] = mfma32(va[3], pb1.v, oacc[1]);
            oacc[2] = mfma32(va[4], pb0.v, oacc[2]);
            oacc[2] = mfma32(va[5], pb1.v, oacc[2]);
            oacc[3] = mfma32(va[6], pb0.v, oacc[3]);
            oacc[3] = mfma32(va[7], pb1.v, oacc[3]);
            __builtin_amdgcn_s_setprio(0);
        }
    }

    // epilogue: each wave owns complete rows — normalize and store directly
    const float lfull = l + swap_partner(l);
    const float inv = 1.f / lfull;
    bf16_t* orow = obuf + ((size_t)b * T_SEQ + i0 + li) * HKDIM + h * DH;
#pragma unroll
    for (int c = 0; c < 4; ++c)
#pragma unroll
        for (int q = 0; q < 4; ++q) {
            bf16x4_t o4;
#pragma unroll
            for (int rr = 0; rr < 4; ++rr)
                o4[rr] = (bf16_t)(oacc[c][4 * q + rr] * inv);
            *(bf16x4_t*)(orow + c * 32 + q * 8 + 4 * hi) = o4;
        }
}

// ---------------------------------------------------------------------------
// Kernel 4: output projection, split-K over waves (unchanged).
// ---------------------------------------------------------------------------
__global__ __launch_bounds__(256) void outproj_kernel(
        const bf16_t* __restrict__ obuf, const bf16_t* __restrict__ wo,
        const float* __restrict__ bo, float* __restrict__ out) {
    const int lane = threadIdx.x & 63, wave = threadIdx.x >> 6;
    const int lr = lane & 15, lq = lane >> 4;
    const int rm0 = blockIdx.x * 16;
    __shared__ float red[4][8][256];   // [wave][g][lane*4]

    f32x4 acc[8];
#pragma unroll
    for (int g = 0; g < 8; ++g) acc[g] = {0.f, 0.f, 0.f, 0.f};
#pragma unroll 2
    for (int k8 = 0; k8 < 8; ++k8) {
        const int kc = wave * 8 + k8;
        bf16x8 aF = *(const bf16x8*)(obuf + (size_t)(rm0 + lr) * HKDIM + kc * 32 + lq * 8);
#pragma unroll
        for (int g = 0; g < 8; ++g) {
            bf16x8 bF = *(const bf16x8*)(wo + (size_t)(g * 16 + lr) * HKDIM + kc * 32 + lq * 8);
            acc[g] = mfma16(aF, bF, acc[g]);
        }
    }
#pragma unroll
    for (int g = 0; g < 8; ++g)
        *(f32x4*)&red[wave][g][lane * 4] = acc[g];
    __syncthreads();
#pragma unroll
    for (int gi = 0; gi < 2; ++gi) {
        const int g = wave * 2 + gi;
        f32x4 s = *(const f32x4*)&red[0][g][lane * 4];
#pragma unroll
        for (int w = 1; w < 4; ++w) {
            f32x4 t = *(const f32x4*)&red[w][g][lane * 4];
            s[0] += t[0]; s[1] += t[1]; s[2] += t[2]; s[3] += t[3];
        }
        const int col = g * 16 + lr;
        const float bias = bo[col];
#pragma unroll
        for (int r = 0; r < 4; ++r) {
            const int row = rm0 + lq * 4 + r;
            const int bb = row >> 10, tt = row & 1023;
            out[((size_t)tt * BATCH + bb) * DH + col] = s[r] + bias;
        }
    }
}

// ---------------------------------------------------------------------------
extern "C" void kernel_launch(void* const* d_in, const int* in_sizes, int n_in,
                              void* d_out, int out_size, void* d_ws, size_t ws_size,
                              hipStream_t stream) {
    const float* x  = (const float*)d_in[0];
    const float* Wk = (const float*)d_in[1];
    const float* bk = (const float*)d_in[2];
    const float* Wq = (const float*)d_in[3];
    const float* bq = (const float*)d_in[4];
    const float* Wv = (const float*)d_in[5];
    const float* bv = (const float*)d_in[6];
    const float* Wo = (const float*)d_in[7];
    const float* bo = (const float*)d_in[8];
    float* out = (float*)d_out;

    char* ws = (char*)d_ws;
    size_t off = 0;
    bf16_t* xb  = (bf16_t*)(ws + off); off += (size_t)BATCH * T_SEQ * DH * 2;       // 2 MiB
    bf16_t* w3  = (bf16_t*)(ws + off); off += (size_t)3 * HKDIM * DH * 2;           // 0.75 MiB
    bf16_t* wo  = (bf16_t*)(ws + off); off += (size_t)DH * HKDIM * 2;               // 0.25 MiB
    bf16_t* kb  = (bf16_t*)(ws + off); off += (size_t)BATCH * NH * T_SEQ * DH * 2;  // 16 MiB
    bf16_t* qb  = (bf16_t*)(ws + off); off += (size_t)BATCH * NH * T_SEQ * DH * 2;  // 16 MiB
    bf16_t* vtb = (bf16_t*)(ws + off); off += (size_t)BATCH * NH * T_SEQ * DH * 2;  // 16 MiB
    bf16_t* ob  = (bf16_t*)(ws + off); off += (size_t)BATCH * T_SEQ * HKDIM * 2;    // 16 MiB

    convert_kernel<<<1536, 256, 0, stream>>>(x, Wk, Wq, Wv, Wo, xb, w3, wo);
    proj_kernel<<<dim3(64, 48), 256, 0, stream>>>(xb, w3, bk, bq, bv, kb, qb, vtb);
    attn_kernel<<<512, 256, 0, stream>>>(kb, qb, vtb, ob);
    outproj_kernel<<<512, 256, 0, stream>>>(ob, wo, bo, out);
}